// Round 1
// baseline (45529.340 us; speedup 1.0000x reference)
//
#include <hip/hip_runtime.h>
#include <hip/hip_bf16.h>
#include <math.h>

// Problem constants
static constexpr int Dm = 1024;   // model dim
static constexpr int Hh = 16;     // heads
static constexpr int HD = 64;     // head dim
static constexpr int Ll = 12;     // layers
static constexpr int Tt = 1024;   // seq len
static constexpr int Bb = 4;      // batch
static constexpr int Vv = 50257;  // vocab
static constexpr int Mrows = Bb * Tt;  // 4096

// ---------------------------------------------------------------- embed
__global__ __launch_bounds__(256)
void embed_kernel(float* __restrict__ x, const float* __restrict__ wte,
                  const float* __restrict__ wpe, const int* __restrict__ idx) {
    int row = blockIdx.x;            // 0..4095
    int t = row & (Tt - 1);
    int id = idx[row];
    int c = threadIdx.x * 4;
    float4 a = *reinterpret_cast<const float4*>(&wte[(size_t)id * Dm + c]);
    float4 p = *reinterpret_cast<const float4*>(&wpe[(size_t)t * Dm + c]);
    float4 o;
    o.x = a.x + p.x; o.y = a.y + p.y; o.z = a.z + p.z; o.w = a.w + p.w;
    *reinterpret_cast<float4*>(&x[(size_t)row * Dm + c]) = o;
}

// ---------------------------------------------------------------- layernorm
__global__ __launch_bounds__(256)
void ln_kernel(float* __restrict__ y, const float* __restrict__ x,
               const float* __restrict__ w, const float* __restrict__ b) {
    int row = blockIdx.x;
    int tid = threadIdx.x;
    const float* xr = x + (size_t)row * Dm;
    float4 v = *reinterpret_cast<const float4*>(&xr[tid * 4]);
    __shared__ float red[256];
    // mean
    red[tid] = v.x + v.y + v.z + v.w;
    __syncthreads();
    for (int s = 128; s > 0; s >>= 1) {
        if (tid < s) red[tid] += red[tid + s];
        __syncthreads();
    }
    float mean = red[0] * (1.0f / Dm);
    __syncthreads();
    // variance of (x - mean)
    float dx = v.x - mean, dy = v.y - mean, dz = v.z - mean, dw = v.w - mean;
    red[tid] = dx * dx + dy * dy + dz * dz + dw * dw;
    __syncthreads();
    for (int s = 128; s > 0; s >>= 1) {
        if (tid < s) red[tid] += red[tid + s];
        __syncthreads();
    }
    float rstd = rsqrtf(red[0] * (1.0f / Dm) + 1e-5f);
    float4 wv = *reinterpret_cast<const float4*>(&w[tid * 4]);
    float4 bv = *reinterpret_cast<const float4*>(&b[tid * 4]);
    float4 o;
    o.x = dx * rstd * wv.x + bv.x;
    o.y = dy * rstd * wv.y + bv.y;
    o.z = dz * rstd * wv.z + bv.z;
    o.w = dw * rstd * wv.w + bv.w;
    *reinterpret_cast<float4*>(&y[(size_t)row * Dm + tid * 4]) = o;
}

// ---------------------------------------------------------------- GEMM
// C[M,N] = A[M,K] @ B + bias, with epilogue.
// BL=0: B stored [K][N] row-major.  BL=1: B stored [N][K] row-major (B^T).
// EPI=0: +bias. EPI=1: +bias then exact GELU. EPI=2: +bias then += R[m][n].
template<int EPI, int BL>
__global__ __launch_bounds__(256)
void gemm_f32(const float* __restrict__ A, const float* __restrict__ B,
              const float* __restrict__ bias, const float* __restrict__ R,
              float* __restrict__ C, int M, int N, int K) {
    constexpr int BM = 64, BN = 64, BK = 16;
    __shared__ float As[BK][BM];
    __shared__ float Bs[BK][BN];
    int tid = threadIdx.x;
    int bm = blockIdx.y * BM;
    int bn = blockIdx.x * BN;
    int tx = tid & 15, ty = tid >> 4;
    float acc[4][4] = {};

    int rowA = tid >> 2;           // 0..63
    int kA = (tid & 3) << 2;       // 0,4,8,12

    for (int k0 = 0; k0 < K; k0 += BK) {
        // A tile: As[k][m] = A[bm+m][k0+k]   (M,K always multiples of tile)
        float4 a4 = *reinterpret_cast<const float4*>(&A[(size_t)(bm + rowA) * K + k0 + kA]);
        As[kA + 0][rowA] = a4.x;
        As[kA + 1][rowA] = a4.y;
        As[kA + 2][rowA] = a4.z;
        As[kA + 3][rowA] = a4.w;
        if (BL == 0) {
            int rb = tid >> 4;         // 0..15
            int nb = (tid & 15) << 2;  // 0..60
            // N multiple of 4 for all BL==0 uses -> aligned float4
            float4 b4 = *reinterpret_cast<const float4*>(&B[(size_t)(k0 + rb) * N + bn + nb]);
            *reinterpret_cast<float4*>(&Bs[rb][nb]) = b4;
        } else {
            int nb = tid >> 2;         // 0..63
            int kb = (tid & 3) << 2;   // 0,4,8,12
            if (bn + nb < N) {
                float4 b4 = *reinterpret_cast<const float4*>(&B[(size_t)(bn + nb) * K + k0 + kb]);
                Bs[kb + 0][nb] = b4.x;
                Bs[kb + 1][nb] = b4.y;
                Bs[kb + 2][nb] = b4.z;
                Bs[kb + 3][nb] = b4.w;
            } else {
                Bs[kb + 0][nb] = 0.f;
                Bs[kb + 1][nb] = 0.f;
                Bs[kb + 2][nb] = 0.f;
                Bs[kb + 3][nb] = 0.f;
            }
        }
        __syncthreads();
#pragma unroll
        for (int kk = 0; kk < BK; ++kk) {
            float4 av = *reinterpret_cast<const float4*>(&As[kk][ty * 4]);
            float4 bv = *reinterpret_cast<const float4*>(&Bs[kk][tx * 4]);
            float ar[4] = {av.x, av.y, av.z, av.w};
            float br[4] = {bv.x, bv.y, bv.z, bv.w};
#pragma unroll
            for (int i = 0; i < 4; ++i)
#pragma unroll
                for (int j = 0; j < 4; ++j) acc[i][j] += ar[i] * br[j];
        }
        __syncthreads();
    }

#pragma unroll
    for (int i = 0; i < 4; ++i) {
        int m = bm + ty * 4 + i;
#pragma unroll
        for (int j = 0; j < 4; ++j) {
            int n = bn + tx * 4 + j;
            if (n >= N) continue;
            float v = acc[i][j] + bias[n];
            if (EPI == 1) v = 0.5f * v * (1.0f + erff(v * 0.70710678118654752f));
            if (EPI == 2) v += R[(size_t)m * N + n];
            C[(size_t)m * N + n] = v;
        }
    }
}

// ---------------------------------------------------------------- attention
// One block per (b,h,q) row. qkv layout: [B*T][3*Dm], q at 0, k at Dm, v at 2*Dm.
__global__ __launch_bounds__(256)
void attn_kernel(const float* __restrict__ qkv, float* __restrict__ o) {
    int bid = blockIdx.x;
    int q = bid & (Tt - 1);
    int h = (bid >> 10) & (Hh - 1);
    int b = bid >> 14;
    int tid = threadIdx.x;

    __shared__ float sc[Tt];
    __shared__ float qs[HD];
    __shared__ float red[256];
    __shared__ float part[4][HD];

    if (tid < HD) qs[tid] = qkv[((size_t)(b * Tt + q)) * 3 * Dm + h * HD + tid];
    __syncthreads();

    const float scale = 0.125f;  // 1/sqrt(64)
    float lmax = -INFINITY;
    for (int k = tid; k <= q; k += 256) {
        const float* kp = &qkv[((size_t)(b * Tt + k)) * 3 * Dm + Dm + h * HD];
        float s = 0.f;
#pragma unroll
        for (int d = 0; d < HD; d += 4) {
            float4 kv = *reinterpret_cast<const float4*>(kp + d);
            s += qs[d] * kv.x + qs[d + 1] * kv.y + qs[d + 2] * kv.z + qs[d + 3] * kv.w;
        }
        s *= scale;
        sc[k] = s;
        lmax = fmaxf(lmax, s);
    }
    red[tid] = lmax;
    __syncthreads();
    for (int s = 128; s > 0; s >>= 1) {
        if (tid < s) red[tid] = fmaxf(red[tid], red[tid + s]);
        __syncthreads();
    }
    float m = red[0];
    __syncthreads();

    float lsum = 0.f;
    for (int k = tid; k <= q; k += 256) {
        float p = expf(sc[k] - m);
        sc[k] = p;
        lsum += p;
    }
    red[tid] = lsum;
    __syncthreads();
    for (int s = 128; s > 0; s >>= 1) {
        if (tid < s) red[tid] += red[tid + s];
        __syncthreads();
    }
    float rinv = 1.0f / red[0];

    int d = tid & (HD - 1);
    int sl = tid >> 6;  // 0..3
    float accv = 0.f;
    for (int k = sl; k <= q; k += 4)
        accv += sc[k] * qkv[((size_t)(b * Tt + k)) * 3 * Dm + 2 * Dm + h * HD + d];
    part[sl][d] = accv;
    __syncthreads();
    if (tid < HD) {
        float r = (part[0][tid] + part[1][tid] + part[2][tid] + part[3][tid]) * rinv;
        o[((size_t)(b * Tt + q)) * Dm + h * HD + tid] = r;
    }
}

// ---------------------------------------------------------------- loss
__global__ __launch_bounds__(256)
void loss_row_kernel(float* __restrict__ nll, const float* __restrict__ logits,
                     const int* __restrict__ targets) {
    int row = blockIdx.x;
    int tid = threadIdx.x;
    const float* lr = logits + (size_t)row * Vv;
    __shared__ float red[256];
    float lmax = -INFINITY;
    for (int j = tid; j < Vv; j += 256) lmax = fmaxf(lmax, lr[j]);
    red[tid] = lmax;
    __syncthreads();
    for (int s = 128; s > 0; s >>= 1) {
        if (tid < s) red[tid] = fmaxf(red[tid], red[tid + s]);
        __syncthreads();
    }
    float m = red[0];
    __syncthreads();
    float lsum = 0.f;
    for (int j = tid; j < Vv; j += 256) lsum += expf(lr[j] - m);
    red[tid] = lsum;
    __syncthreads();
    for (int s = 128; s > 0; s >>= 1) {
        if (tid < s) red[tid] += red[tid + s];
        __syncthreads();
    }
    if (tid == 0) {
        float lse = m + logf(red[0]);
        nll[row] = lse - lr[targets[row]];
    }
}

__global__ __launch_bounds__(256)
void loss_reduce_kernel(float* __restrict__ loss, const float* __restrict__ nll) {
    int tid = threadIdx.x;
    __shared__ float red[256];
    float s = 0.f;
    for (int j = tid; j < Mrows; j += 256) s += nll[j];
    red[tid] = s;
    __syncthreads();
    for (int st = 128; st > 0; st >>= 1) {
        if (tid < st) red[tid] += red[tid + st];
        __syncthreads();
    }
    if (tid == 0) *loss = red[0] * (1.0f / Mrows);
}

// ---------------------------------------------------------------- launch
extern "C" void kernel_launch(void* const* d_in, const int* in_sizes, int n_in,
                              void* d_out, int out_size, void* d_ws, size_t ws_size,
                              hipStream_t stream) {
    const int* idx = (const int*)d_in[0];
    const int* targets = (const int*)d_in[1];
    const float* wte = (const float*)d_in[2];
    const float* wpe = (const float*)d_in[3];
    const float* ln1_w = (const float*)d_in[4];
    const float* ln1_b = (const float*)d_in[5];
    const float* qkv_w = (const float*)d_in[6];
    const float* qkv_b = (const float*)d_in[7];
    const float* o_w = (const float*)d_in[8];
    const float* o_b = (const float*)d_in[9];
    const float* ln2_w = (const float*)d_in[10];
    const float* ln2_b = (const float*)d_in[11];
    const float* up_w = (const float*)d_in[12];
    const float* up_b = (const float*)d_in[13];
    const float* down_w = (const float*)d_in[14];
    const float* down_b = (const float*)d_in[15];
    const float* lnf_w = (const float*)d_in[16];
    const float* lnf_b = (const float*)d_in[17];
    const float* lm_b = (const float*)d_in[18];

    float* logits = (float*)d_out;

    char* ws = (char*)d_ws;
    const size_t MB = 1024 * 1024;
    float* x   = (float*)(ws + 0 * MB);     // 16 MB  [4096,1024] residual stream
    float* y   = (float*)(ws + 16 * MB);    // 16 MB  [4096,1024] LN out
    float* qkv = (float*)(ws + 32 * MB);    // 48 MB  [4096,3072]
    float* ob  = (float*)(ws + 80 * MB);    // 16 MB  [4096,1024] attn out
    float* up  = (float*)(ws + 96 * MB);    // 64 MB  [4096,4096]
    float* nll = (float*)(ws + 160 * MB);   // 16 KB  [4096]

    embed_kernel<<<Mrows, 256, 0, stream>>>(x, wte, wpe, idx);

    for (int l = 0; l < Ll; ++l) {
        ln_kernel<<<Mrows, 256, 0, stream>>>(y, x, ln1_w + l * Dm, ln1_b + l * Dm);
        gemm_f32<0, 0><<<dim3(3 * Dm / 64, Mrows / 64), 256, 0, stream>>>(
            y, qkv_w + (size_t)l * Dm * 3 * Dm, qkv_b + (size_t)l * 3 * Dm, nullptr, qkv,
            Mrows, 3 * Dm, Dm);
        attn_kernel<<<Bb * Hh * Tt, 256, 0, stream>>>(qkv, ob);
        gemm_f32<2, 0><<<dim3(Dm / 64, Mrows / 64), 256, 0, stream>>>(
            ob, o_w + (size_t)l * Dm * Dm, o_b + (size_t)l * Dm, x, x, Mrows, Dm, Dm);
        ln_kernel<<<Mrows, 256, 0, stream>>>(y, x, ln2_w + l * Dm, ln2_b + l * Dm);
        gemm_f32<1, 0><<<dim3(4 * Dm / 64, Mrows / 64), 256, 0, stream>>>(
            y, up_w + (size_t)l * Dm * 4 * Dm, up_b + (size_t)l * 4 * Dm, nullptr, up,
            Mrows, 4 * Dm, Dm);
        gemm_f32<2, 0><<<dim3(Dm / 64, Mrows / 64), 256, 0, stream>>>(
            up, down_w + (size_t)l * 4 * Dm * Dm, down_b + (size_t)l * Dm, x, x,
            Mrows, Dm, 4 * Dm);
    }

    ln_kernel<<<Mrows, 256, 0, stream>>>(y, x, lnf_w, lnf_b);
    gemm_f32<0, 1><<<dim3((Vv + 63) / 64, Mrows / 64), 256, 0, stream>>>(
        y, wte, lm_b, nullptr, logits, Mrows, Vv, Dm);
    loss_row_kernel<<<Mrows, 256, 0, stream>>>(nll, logits, targets);
    loss_reduce_kernel<<<1, 256, 0, stream>>>(logits + (size_t)Mrows * Vv, nll);
}

// Round 2
// 10228.384 us; speedup vs baseline: 4.4513x; 4.4513x over previous
//
#include <hip/hip_runtime.h>
#include <hip/hip_bf16.h>
#include <math.h>

typedef __attribute__((ext_vector_type(8))) short bfrag;   // 8 bf16 (4 VGPRs)
typedef __attribute__((ext_vector_type(4))) float f32x4;

static constexpr int Dm = 1024, Hh = 16, HD = 64, Ll = 12, Tt = 1024, Bb = 4;
static constexpr int Vv = 50257, Mrows = 4096;

__device__ inline unsigned short f2bf(float f) {  // RNE f32->bf16
    unsigned u = __float_as_uint(f);
    u += 0x7fffu + ((u >> 16) & 1u);
    return (unsigned short)(u >> 16);
}
__device__ inline float bf2f(unsigned short s) {
    return __uint_as_float(((unsigned)s) << 16);
}

// ---------------------------------------------------------------- embed (f32)
__global__ __launch_bounds__(256)
void embed_kernel(float* __restrict__ x, const float* __restrict__ wte,
                  const float* __restrict__ wpe, const int* __restrict__ idx) {
    int row = blockIdx.x;
    int t = row & (Tt - 1);
    int id = idx[row];
    int c = threadIdx.x * 4;
    float4 a = *reinterpret_cast<const float4*>(&wte[(size_t)id * Dm + c]);
    float4 p = *reinterpret_cast<const float4*>(&wpe[(size_t)t * Dm + c]);
    float4 o;
    o.x = a.x + p.x; o.y = a.y + p.y; o.z = a.z + p.z; o.w = a.w + p.w;
    *reinterpret_cast<float4*>(&x[(size_t)row * Dm + c]) = o;
}

// ---------------------------------------------------------------- layernorm: f32 in, bf16 out
__global__ __launch_bounds__(256)
void ln_kernel(unsigned short* __restrict__ y, const float* __restrict__ x,
               const float* __restrict__ w, const float* __restrict__ b) {
    int row = blockIdx.x;
    int tid = threadIdx.x;
    const float* xr = x + (size_t)row * Dm;
    float4 v = *reinterpret_cast<const float4*>(&xr[tid * 4]);
    __shared__ float red[256];
    red[tid] = v.x + v.y + v.z + v.w;
    __syncthreads();
    for (int s = 128; s > 0; s >>= 1) {
        if (tid < s) red[tid] += red[tid + s];
        __syncthreads();
    }
    float mean = red[0] * (1.0f / Dm);
    __syncthreads();
    float dx = v.x - mean, dy = v.y - mean, dz = v.z - mean, dw = v.w - mean;
    red[tid] = dx * dx + dy * dy + dz * dz + dw * dw;
    __syncthreads();
    for (int s = 128; s > 0; s >>= 1) {
        if (tid < s) red[tid] += red[tid + s];
        __syncthreads();
    }
    float rstd = rsqrtf(red[0] * (1.0f / Dm) + 1e-5f);
    float4 wv = *reinterpret_cast<const float4*>(&w[tid * 4]);
    float4 bv = *reinterpret_cast<const float4*>(&b[tid * 4]);
    ushort4 o;
    o.x = f2bf(dx * rstd * wv.x + bv.x);
    o.y = f2bf(dy * rstd * wv.y + bv.y);
    o.z = f2bf(dz * rstd * wv.z + bv.z);
    o.w = f2bf(dw * rstd * wv.w + bv.w);
    *reinterpret_cast<ushort4*>(&y[(size_t)row * Dm + tid * 4]) = o;
}

// ------------------------------------------------- weight transpose+convert
// w[K][N] f32 (row-major) -> wT[N][K] bf16. grid (N/32, K/32), 256 thr.
__global__ __launch_bounds__(256)
void transpose_k(unsigned short* __restrict__ wT, const float* __restrict__ w,
                 int K, int N) {
    __shared__ float t[32][33];
    int n0 = blockIdx.x * 32, k0 = blockIdx.y * 32;
    int tid = threadIdx.x;
    int r = tid >> 3, c4 = (tid & 7) * 4;
    float4 v = *reinterpret_cast<const float4*>(&w[(size_t)(k0 + r) * N + n0 + c4]);
    t[r][c4] = v.x; t[r][c4 + 1] = v.y; t[r][c4 + 2] = v.z; t[r][c4 + 3] = v.w;
    __syncthreads();
    int nr = tid >> 3, kc = (tid & 7) * 4;
    ushort4 o;
    o.x = f2bf(t[kc][nr]);
    o.y = f2bf(t[kc + 1][nr]);
    o.z = f2bf(t[kc + 2][nr]);
    o.w = f2bf(t[kc + 3][nr]);
    *reinterpret_cast<ushort4*>(&wT[(size_t)(n0 + nr) * K + k0 + kc]) = o;
}

// ---------------------------------------------------------------- MFMA GEMM
// C[M,N] = A[M,K](bf16) @ B[N,K]^T + bias.
// BF32=0: B bf16 [N][K]. BF32=1: B f32 [N][K] (wte), cvt during staging, guard N.
// EPI 0: C bf16 = acc+bias. 1: C bf16 = gelu(acc+bias).
// EPI 2: C f32 = R + acc + bias. 3: C f32 = acc+bias, guard col<N.
template<int EPI, int BF32>
__global__ __launch_bounds__(256)
void gemm_mfma(const unsigned short* __restrict__ A, const void* __restrict__ Bp,
               const float* __restrict__ bias, const float* __restrict__ R,
               void* __restrict__ Cp, int M, int N, int K) {
    __shared__ unsigned short As[128 * 32];
    __shared__ unsigned short Bs[128 * 32];
    const int tid = threadIdx.x;
    const int bm = blockIdx.x * 128;
    const int bn = blockIdx.y * 128;
    const int lane = tid & 63, wid = tid >> 6;
    const int wr = wid >> 1, wc = wid & 1;
    const int g = lane >> 4, lr = lane & 15;
    const unsigned short* B16 = (const unsigned short*)Bp;
    const float* Bf = (const float*)Bp;

    f32x4 acc[4][4];
#pragma unroll
    for (int i = 0; i < 4; ++i)
#pragma unroll
        for (int j = 0; j < 4; ++j)
#pragma unroll
            for (int r = 0; r < 4; ++r) acc[i][j][r] = 0.f;

    for (int k0 = 0; k0 < K; k0 += 32) {
#pragma unroll
        for (int it = 0; it < 2; ++it) {
            int c = tid + it * 256;
            int row = c >> 2, slot = c & 3;
            int dst = row * 32 + ((slot ^ (row & 3)) * 8);
            bfrag av = *reinterpret_cast<const bfrag*>(&A[(size_t)(bm + row) * K + k0 + slot * 8]);
            *reinterpret_cast<bfrag*>(&As[dst]) = av;
            if (!BF32) {
                bfrag bv = *reinterpret_cast<const bfrag*>(&B16[(size_t)(bn + row) * K + k0 + slot * 8]);
                *reinterpret_cast<bfrag*>(&Bs[dst]) = bv;
            } else {
                bfrag bv;
                if (bn + row < N) {
                    const float* src = &Bf[(size_t)(bn + row) * K + k0 + slot * 8];
                    float4 f0 = *reinterpret_cast<const float4*>(src);
                    float4 f1 = *reinterpret_cast<const float4*>(src + 4);
                    bv[0] = (short)f2bf(f0.x); bv[1] = (short)f2bf(f0.y);
                    bv[2] = (short)f2bf(f0.z); bv[3] = (short)f2bf(f0.w);
                    bv[4] = (short)f2bf(f1.x); bv[5] = (short)f2bf(f1.y);
                    bv[6] = (short)f2bf(f1.z); bv[7] = (short)f2bf(f1.w);
                } else {
#pragma unroll
                    for (int i = 0; i < 8; ++i) bv[i] = 0;
                }
                *reinterpret_cast<bfrag*>(&Bs[dst]) = bv;
            }
        }
        __syncthreads();
        bfrag af[4], bf_[4];
#pragma unroll
        for (int i = 0; i < 4; ++i) {
            int ra = wr * 64 + i * 16 + lr;
            af[i] = *reinterpret_cast<const bfrag*>(&As[ra * 32 + ((g ^ (ra & 3)) * 8)]);
            int rb = wc * 64 + i * 16 + lr;
            bf_[i] = *reinterpret_cast<const bfrag*>(&Bs[rb * 32 + ((g ^ (rb & 3)) * 8)]);
        }
#pragma unroll
        for (int mi = 0; mi < 4; ++mi)
#pragma unroll
            for (int ni = 0; ni < 4; ++ni)
                acc[mi][ni] = __builtin_amdgcn_mfma_f32_16x16x32_bf16(af[mi], bf_[ni], acc[mi][ni], 0, 0, 0);
        __syncthreads();
    }

    unsigned short* Cb = (unsigned short*)Cp;
    float* Cf = (float*)Cp;
#pragma unroll
    for (int ni = 0; ni < 4; ++ni) {
        int col = bn + wc * 64 + ni * 16 + lr;
        if (EPI == 3 && col >= N) continue;
        float bi = bias[col];
#pragma unroll
        for (int mi = 0; mi < 4; ++mi) {
            int row0 = bm + wr * 64 + mi * 16 + g * 4;
#pragma unroll
            for (int r = 0; r < 4; ++r) {
                int row = row0 + r;
                float v = acc[mi][ni][r] + bi;
                if (EPI == 0) {
                    Cb[(size_t)row * N + col] = f2bf(v);
                } else if (EPI == 1) {
                    v = 0.5f * v * (1.0f + erff(v * 0.70710678118654752f));
                    Cb[(size_t)row * N + col] = f2bf(v);
                } else if (EPI == 2) {
                    Cf[(size_t)row * N + col] = R[(size_t)row * N + col] + v;
                } else {
                    Cf[(size_t)row * N + col] = v;
                }
            }
        }
    }
}

// ---------------------------------------------------------------- attention
// q-tiled flash-style, f32 VALU compute, bf16 I/O. One block per (b,h,qtile64).
__global__ __launch_bounds__(256)
void attn64(const unsigned short* __restrict__ qkv, unsigned short* __restrict__ ob) {
    int bid = blockIdx.x;
    int qt = bid & 15, h = (bid >> 4) & 15, b = bid >> 8;
    int tid = threadIdx.x;
    int q = tid >> 2, ks = tid & 3;
    __shared__ float Qt[64][68];
    __shared__ float KV[64][68];
    __shared__ float sP[64][68];
    {
        int row = tid >> 2, d0 = (tid & 3) * 16;
        const unsigned short* src = &qkv[((size_t)(b * Tt + qt * 64 + row)) * 3072 + h * 64 + d0];
        bfrag v0 = *(const bfrag*)src;
        bfrag v1 = *(const bfrag*)(src + 8);
#pragma unroll
        for (int i = 0; i < 8; ++i) Qt[row][d0 + i] = bf2f((unsigned short)v0[i]) * 0.125f;
#pragma unroll
        for (int i = 0; i < 8; ++i) Qt[row][d0 + 8 + i] = bf2f((unsigned short)v1[i]) * 0.125f;
    }
    float m = -3.0e38f, l = 0.f;
    float Ov[16];
#pragma unroll
    for (int i = 0; i < 16; ++i) Ov[i] = 0.f;
    int qglob = qt * 64 + q;

    for (int kt = 0; kt <= qt; ++kt) {
        {   // stage K (row-permuted: pr = ((k&15)<<2)|(k>>4))
            int row = tid >> 2, d0 = (tid & 3) * 16;
            int pr = ((row & 15) << 2) | (row >> 4);
            const unsigned short* src = &qkv[((size_t)(b * Tt + kt * 64 + row)) * 3072 + Dm + h * 64 + d0];
            bfrag v0 = *(const bfrag*)src;
            bfrag v1 = *(const bfrag*)(src + 8);
#pragma unroll
            for (int i = 0; i < 8; ++i) KV[pr][d0 + i] = bf2f((unsigned short)v0[i]);
#pragma unroll
            for (int i = 0; i < 8; ++i) KV[pr][d0 + 8 + i] = bf2f((unsigned short)v1[i]);
        }
        __syncthreads();
        float sc[16];
#pragma unroll
        for (int i = 0; i < 16; ++i) sc[i] = 0.f;
        for (int d0 = 0; d0 < 64; d0 += 4) {
            float4 qv = *reinterpret_cast<const float4*>(&Qt[q][d0]);
#pragma unroll
            for (int i = 0; i < 16; ++i) {
                int krow = (i << 2) | ks;
                float4 kv = *reinterpret_cast<const float4*>(&KV[krow][d0]);
                sc[i] += qv.x * kv.x + qv.y * kv.y + qv.z * kv.z + qv.w * kv.w;
            }
        }
        if (kt == qt) {
#pragma unroll
            for (int i = 0; i < 16; ++i)
                if (kt * 64 + ks * 16 + i > qglob) sc[i] = -3.0e38f;
        }
        float tmax = sc[0];
#pragma unroll
        for (int i = 1; i < 16; ++i) tmax = fmaxf(tmax, sc[i]);
        tmax = fmaxf(tmax, __shfl_xor(tmax, 1));
        tmax = fmaxf(tmax, __shfl_xor(tmax, 2));
        float mnew = fmaxf(m, tmax);
        float scale = expf(m - mnew);
        float psum = 0.f;
#pragma unroll
        for (int i = 0; i < 16; i += 4) {
            float4 pv;
            pv.x = expf(sc[i] - mnew);
            pv.y = expf(sc[i + 1] - mnew);
            pv.z = expf(sc[i + 2] - mnew);
            pv.w = expf(sc[i + 3] - mnew);
            psum += pv.x + pv.y + pv.z + pv.w;
            *reinterpret_cast<float4*>(&sP[q][ks * 16 + i]) = pv;
        }
        psum += __shfl_xor(psum, 1);
        psum += __shfl_xor(psum, 2);
        l = l * scale + psum;
        m = mnew;
#pragma unroll
        for (int i = 0; i < 16; ++i) Ov[i] *= scale;
        __syncthreads();
        {   // stage V (overwrite KV), same permutation
            int row = tid >> 2, d0 = (tid & 3) * 16;
            int pr = ((row & 15) << 2) | (row >> 4);
            const unsigned short* src = &qkv[((size_t)(b * Tt + kt * 64 + row)) * 3072 + 2 * Dm + h * 64 + d0];
            bfrag v0 = *(const bfrag*)src;
            bfrag v1 = *(const bfrag*)(src + 8);
#pragma unroll
            for (int i = 0; i < 8; ++i) KV[pr][d0 + i] = bf2f((unsigned short)v0[i]);
#pragma unroll
            for (int i = 0; i < 8; ++i) KV[pr][d0 + 8 + i] = bf2f((unsigned short)v1[i]);
        }
        __syncthreads();
        for (int k = 0; k < 64; ++k) {
            float p = sP[q][k];
            int pr = ((k & 15) << 2) | (k >> 4);
#pragma unroll
            for (int j = 0; j < 4; ++j) {
                float4 vv = *reinterpret_cast<const float4*>(&KV[pr][ks * 16 + j * 4]);
                Ov[j * 4 + 0] += p * vv.x;
                Ov[j * 4 + 1] += p * vv.y;
                Ov[j * 4 + 2] += p * vv.z;
                Ov[j * 4 + 3] += p * vv.w;
            }
        }
        __syncthreads();
    }
    float rinv = 1.0f / l;
    unsigned short* dst = &ob[((size_t)(b * Tt + qglob)) * Dm + h * 64 + ks * 16];
#pragma unroll
    for (int i = 0; i < 8; ++i) {
        unsigned lo = f2bf(Ov[2 * i] * rinv), hi = f2bf(Ov[2 * i + 1] * rinv);
        *reinterpret_cast<unsigned*>(dst + 2 * i) = lo | (hi << 16);
    }
}

// ---------------------------------------------------------------- loss
__global__ __launch_bounds__(256)
void loss_row_kernel(float* __restrict__ nll, const float* __restrict__ logits,
                     const int* __restrict__ targets) {
    int row = blockIdx.x;
    int tid = threadIdx.x;
    const float* lr = logits + (size_t)row * Vv;
    __shared__ float red[256];
    float lmax = -INFINITY;
    for (int j = tid; j < Vv; j += 256) lmax = fmaxf(lmax, lr[j]);
    red[tid] = lmax;
    __syncthreads();
    for (int s = 128; s > 0; s >>= 1) {
        if (tid < s) red[tid] = fmaxf(red[tid], red[tid + s]);
        __syncthreads();
    }
    float m = red[0];
    __syncthreads();
    float lsum = 0.f;
    for (int j = tid; j < Vv; j += 256) lsum += expf(lr[j] - m);
    red[tid] = lsum;
    __syncthreads();
    for (int s = 128; s > 0; s >>= 1) {
        if (tid < s) red[tid] += red[tid + s];
        __syncthreads();
    }
    if (tid == 0) {
        float lse = m + logf(red[0]);
        nll[row] = lse - lr[targets[row]];
    }
}

__global__ __launch_bounds__(256)
void loss_reduce_kernel(float* __restrict__ loss, const float* __restrict__ nll) {
    int tid = threadIdx.x;
    __shared__ float red[256];
    float s = 0.f;
    for (int j = tid; j < Mrows; j += 256) s += nll[j];
    red[tid] = s;
    __syncthreads();
    for (int st = 128; st > 0; st >>= 1) {
        if (tid < st) red[tid] += red[tid + st];
        __syncthreads();
    }
    if (tid == 0) *loss = red[0] * (1.0f / Mrows);
}

// ---------------------------------------------------------------- launch
extern "C" void kernel_launch(void* const* d_in, const int* in_sizes, int n_in,
                              void* d_out, int out_size, void* d_ws, size_t ws_size,
                              hipStream_t stream) {
    const int* idx = (const int*)d_in[0];
    const int* targets = (const int*)d_in[1];
    const float* wte = (const float*)d_in[2];
    const float* wpe = (const float*)d_in[3];
    const float* ln1_w = (const float*)d_in[4];
    const float* ln1_b = (const float*)d_in[5];
    const float* qkv_w = (const float*)d_in[6];
    const float* qkv_b = (const float*)d_in[7];
    const float* o_w = (const float*)d_in[8];
    const float* o_b = (const float*)d_in[9];
    const float* ln2_w = (const float*)d_in[10];
    const float* ln2_b = (const float*)d_in[11];
    const float* up_w = (const float*)d_in[12];
    const float* up_b = (const float*)d_in[13];
    const float* down_w = (const float*)d_in[14];
    const float* down_b = (const float*)d_in[15];
    const float* lnf_w = (const float*)d_in[16];
    const float* lnf_b = (const float*)d_in[17];
    const float* lm_b = (const float*)d_in[18];

    float* logits = (float*)d_out;
    char* ws = (char*)d_ws;
    const size_t MB = 1 << 20;
    float* x            = (float*)(ws);                       // 16 MB
    unsigned short* y   = (unsigned short*)(ws + 16 * MB);    // 8 MB
    unsigned short* qkv = (unsigned short*)(ws + 24 * MB);    // 24 MB
    unsigned short* ob  = (unsigned short*)(ws + 48 * MB);    // 8 MB
    unsigned short* up  = (unsigned short*)(ws + 56 * MB);    // 32 MB
    unsigned short* wTq = (unsigned short*)(ws + 88 * MB);    // 6.3 MB
    unsigned short* wTo = (unsigned short*)(ws + 96 * MB);    // 2.1 MB
    unsigned short* wTu = (unsigned short*)(ws + 100 * MB);   // 8.4 MB
    unsigned short* wTd = (unsigned short*)(ws + 112 * MB);   // 8.4 MB
    float* nll          = (float*)(ws + 124 * MB);            // 16 KB

    embed_kernel<<<Mrows, 256, 0, stream>>>(x, wte, wpe, idx);

    for (int l = 0; l < Ll; ++l) {
        ln_kernel<<<Mrows, 256, 0, stream>>>(y, x, ln1_w + l * Dm, ln1_b + l * Dm);
        transpose_k<<<dim3(3 * Dm / 32, Dm / 32), 256, 0, stream>>>(
            wTq, qkv_w + (size_t)l * Dm * 3 * Dm, Dm, 3 * Dm);
        gemm_mfma<0, 0><<<dim3(Mrows / 128, 3 * Dm / 128), 256, 0, stream>>>(
            y, wTq, qkv_b + (size_t)l * 3 * Dm, nullptr, qkv, Mrows, 3 * Dm, Dm);
        attn64<<<Bb * Hh * 16, 256, 0, stream>>>(qkv, ob);
        transpose_k<<<dim3(Dm / 32, Dm / 32), 256, 0, stream>>>(
            wTo, o_w + (size_t)l * Dm * Dm, Dm, Dm);
        gemm_mfma<2, 0><<<dim3(Mrows / 128, Dm / 128), 256, 0, stream>>>(
            ob, wTo, o_b + (size_t)l * Dm, x, x, Mrows, Dm, Dm);
        ln_kernel<<<Mrows, 256, 0, stream>>>(y, x, ln2_w + l * Dm, ln2_b + l * Dm);
        transpose_k<<<dim3(4 * Dm / 32, Dm / 32), 256, 0, stream>>>(
            wTu, up_w + (size_t)l * Dm * 4 * Dm, Dm, 4 * Dm);
        gemm_mfma<1, 0><<<dim3(Mrows / 128, 4 * Dm / 128), 256, 0, stream>>>(
            y, wTu, up_b + (size_t)l * 4 * Dm, nullptr, up, Mrows, 4 * Dm, Dm);
        transpose_k<<<dim3(Dm / 32, 4 * Dm / 32), 256, 0, stream>>>(
            wTd, down_w + (size_t)l * 4 * Dm * Dm, 4 * Dm, Dm);
        gemm_mfma<2, 0><<<dim3(Mrows / 128, Dm / 128), 256, 0, stream>>>(
            up, wTd, down_b + (size_t)l * Dm, x, x, Mrows, Dm, 4 * Dm);
    }

    ln_kernel<<<Mrows, 256, 0, stream>>>(y, x, lnf_w, lnf_b);
    gemm_mfma<3, 1><<<dim3(Mrows / 128, (Vv + 127) / 128), 256, 0, stream>>>(
        y, wte, lm_b, nullptr, logits, Mrows, Vv, Dm);
    loss_row_kernel<<<Mrows, 256, 0, stream>>>(nll, logits, targets);
    loss_reduce_kernel<<<1, 256, 0, stream>>>(logits + (size_t)Mrows * Vv, nll);
}

// Round 3
// 5613.710 us; speedup vs baseline: 8.1104x; 1.8220x over previous
//
#include <hip/hip_runtime.h>
#include <hip/hip_bf16.h>
#include <math.h>

typedef __attribute__((ext_vector_type(8))) short bfrag;   // 8 bf16 (4 VGPRs)
typedef __attribute__((ext_vector_type(4))) float f32x4;

static constexpr int Dm = 1024, Hh = 16, HD = 64, Ll = 12, Tt = 1024, Bb = 4;
static constexpr int Vv = 50257, Mrows = 4096;

__device__ inline unsigned short f2bf(float f) {  // RNE f32->bf16
    unsigned u = __float_as_uint(f);
    u += 0x7fffu + ((u >> 16) & 1u);
    return (unsigned short)(u >> 16);
}
__device__ inline float bf2f(unsigned short s) {
    return __uint_as_float(((unsigned)s) << 16);
}

__device__ inline void gload16(const unsigned short* g, unsigned short* l) {
    __builtin_amdgcn_global_load_lds(
        (const __attribute__((address_space(1))) void*)g,
        (__attribute__((address_space(3))) void*)l, 16, 0, 0);
}

// ---------------------------------------------------------------- embed (f32)
__global__ __launch_bounds__(256)
void embed_kernel(float* __restrict__ x, const float* __restrict__ wte,
                  const float* __restrict__ wpe, const int* __restrict__ idx) {
    int row = blockIdx.x;
    int t = row & (Tt - 1);
    int id = idx[row];
    int c = threadIdx.x * 4;
    float4 a = *reinterpret_cast<const float4*>(&wte[(size_t)id * Dm + c]);
    float4 p = *reinterpret_cast<const float4*>(&wpe[(size_t)t * Dm + c]);
    float4 o;
    o.x = a.x + p.x; o.y = a.y + p.y; o.z = a.z + p.z; o.w = a.w + p.w;
    *reinterpret_cast<float4*>(&x[(size_t)row * Dm + c]) = o;
}

// ---------------------------------------------------------------- layernorm: f32 in, bf16 out
__global__ __launch_bounds__(256)
void ln_kernel(unsigned short* __restrict__ y, const float* __restrict__ x,
               const float* __restrict__ w, const float* __restrict__ b) {
    int row = blockIdx.x;
    int tid = threadIdx.x;
    const float* xr = x + (size_t)row * Dm;
    float4 v = *reinterpret_cast<const float4*>(&xr[tid * 4]);
    __shared__ float red[256];
    red[tid] = v.x + v.y + v.z + v.w;
    __syncthreads();
    for (int s = 128; s > 0; s >>= 1) {
        if (tid < s) red[tid] += red[tid + s];
        __syncthreads();
    }
    float mean = red[0] * (1.0f / Dm);
    __syncthreads();
    float dx = v.x - mean, dy = v.y - mean, dz = v.z - mean, dw = v.w - mean;
    red[tid] = dx * dx + dy * dy + dz * dz + dw * dw;
    __syncthreads();
    for (int s = 128; s > 0; s >>= 1) {
        if (tid < s) red[tid] += red[tid + s];
        __syncthreads();
    }
    float rstd = rsqrtf(red[0] * (1.0f / Dm) + 1e-5f);
    float4 wv = *reinterpret_cast<const float4*>(&w[tid * 4]);
    float4 bv = *reinterpret_cast<const float4*>(&b[tid * 4]);
    ushort4 o;
    o.x = f2bf(dx * rstd * wv.x + bv.x);
    o.y = f2bf(dy * rstd * wv.y + bv.y);
    o.z = f2bf(dz * rstd * wv.z + bv.z);
    o.w = f2bf(dw * rstd * wv.w + bv.w);
    *reinterpret_cast<ushort4*>(&y[(size_t)row * Dm + tid * 4]) = o;
}

// ------------------------------------------------- weight transpose+convert
// w[K][N] f32 -> wT[N][K] bf16. grid (N/32, K/32), 256 thr.
__global__ __launch_bounds__(256)
void transpose_k(unsigned short* __restrict__ wT, const float* __restrict__ w,
                 int K, int N) {
    __shared__ float t[32][33];
    int n0 = blockIdx.x * 32, k0 = blockIdx.y * 32;
    int tid = threadIdx.x;
    int r = tid >> 3, c4 = (tid & 7) * 4;
    float4 v = *reinterpret_cast<const float4*>(&w[(size_t)(k0 + r) * N + n0 + c4]);
    t[r][c4] = v.x; t[r][c4 + 1] = v.y; t[r][c4 + 2] = v.z; t[r][c4 + 3] = v.w;
    __syncthreads();
    int nr = tid >> 3, kc = (tid & 7) * 4;
    ushort4 o;
    o.x = f2bf(t[kc][nr]);
    o.y = f2bf(t[kc + 1][nr]);
    o.z = f2bf(t[kc + 2][nr]);
    o.w = f2bf(t[kc + 3][nr]);
    *reinterpret_cast<ushort4*>(&wT[(size_t)(n0 + nr) * K + k0 + kc]) = o;
}

// ------------------------------------------------- f32 rows -> bf16 rows (lm_head chunks)
__global__ __launch_bounds__(128)
void cvt_rows(unsigned short* __restrict__ dst, const float* __restrict__ src) {
    int row = blockIdx.x;
    int t = threadIdx.x;
    const float* s = src + (size_t)row * Dm + t * 8;
    float4 f0 = *reinterpret_cast<const float4*>(s);
    float4 f1 = *reinterpret_cast<const float4*>(s + 4);
    ushort4 o0, o1;
    o0.x = f2bf(f0.x); o0.y = f2bf(f0.y); o0.z = f2bf(f0.z); o0.w = f2bf(f0.w);
    o1.x = f2bf(f1.x); o1.y = f2bf(f1.y); o1.z = f2bf(f1.z); o1.w = f2bf(f1.w);
    unsigned short* d = dst + (size_t)row * Dm + t * 8;
    *reinterpret_cast<ushort4*>(d) = o0;
    *reinterpret_cast<ushort4*>(d + 4) = o1;
}

// ---------------------------------------------------------------- MFMA GEMM (m97 structure)
// C[M,*] = A[M,K](bf16) @ B[Nv,K]^T(bf16) + bias, 128x128 tile, BK=32,
// global_load_lds staging, linear LDS.
// EPI 0: C bf16 = acc+bias. 1: C bf16 = gelu(acc+bias). 2: C f32 = R+acc+bias.
// 3: C f32 = acc+bias. GN: guard cols against Nv (B rows clamped).
// Output col = ncol + local col, C leading dim = ldc. bias indexed globally.
template<int EPI, int GN>
__global__ __launch_bounds__(256)
void gemm_mfma(const unsigned short* __restrict__ A, const unsigned short* __restrict__ B,
               const float* __restrict__ bias, const float* __restrict__ R,
               void* __restrict__ Cp, int M, int Nv, int K, int ldc, int ncol) {
    __shared__ unsigned short As[128 * 32];
    __shared__ unsigned short Bs[128 * 32];
    const int tid = threadIdx.x;
    const int lane = tid & 63, wid = tid >> 6;
    const int bm = blockIdx.x * 128;
    const int bn = blockIdx.y * 128;
    const int wr = wid >> 1, wc = wid & 1;
    const int g = lane >> 4, lr = lane & 15;
    const int l4 = lane >> 2, ksl = lane & 3;

    f32x4 acc[4][4];
#pragma unroll
    for (int i = 0; i < 4; ++i)
#pragma unroll
        for (int j = 0; j < 4; ++j)
#pragma unroll
            for (int r = 0; r < 4; ++r) acc[i][j][r] = 0.f;

    for (int k0 = 0; k0 < K; k0 += 32) {
        // wave wid stages loads j = wid*4 .. wid*4+3 (j<8: A rows, else B rows)
#pragma unroll
        for (int jj = 0; jj < 4; ++jj) {
            int j = wid * 4 + jj;
            if (j < 8) {
                int row = j * 16 + l4;
                gload16(&A[(size_t)(bm + row) * K + k0 + ksl * 8], &As[j * 512]);
            } else {
                int j8 = j - 8;
                int row = j8 * 16 + l4;
                int grow = bn + row;
                if (GN) grow = (grow < Nv) ? grow : (Nv - 1);
                gload16(&B[(size_t)grow * K + k0 + ksl * 8], &Bs[j8 * 512]);
            }
        }
        __syncthreads();
        bfrag af[4], bfr[4];
#pragma unroll
        for (int i = 0; i < 4; ++i) {
            int ra = wr * 64 + i * 16 + lr;
            af[i] = *reinterpret_cast<const bfrag*>(&As[ra * 32 + g * 8]);
            int rb = wc * 64 + i * 16 + lr;
            bfr[i] = *reinterpret_cast<const bfrag*>(&Bs[rb * 32 + g * 8]);
        }
#pragma unroll
        for (int mi = 0; mi < 4; ++mi)
#pragma unroll
            for (int ni = 0; ni < 4; ++ni)
                acc[mi][ni] = __builtin_amdgcn_mfma_f32_16x16x32_bf16(af[mi], bfr[ni], acc[mi][ni], 0, 0, 0);
        __syncthreads();
    }

    unsigned short* Cb = (unsigned short*)Cp;
    float* Cf = (float*)Cp;
#pragma unroll
    for (int ni = 0; ni < 4; ++ni) {
        int col = wc * 64 + ni * 16 + lr + (blockIdx.y * 128);
        if (GN && col >= Nv) continue;
        int gcol = ncol + col;
        float bi = bias[gcol];
#pragma unroll
        for (int mi = 0; mi < 4; ++mi) {
            int row0 = bm + wr * 64 + mi * 16 + g * 4;
#pragma unroll
            for (int r = 0; r < 4; ++r) {
                int row = row0 + r;
                float v = acc[mi][ni][r] + bi;
                if (EPI == 0) {
                    Cb[(size_t)row * ldc + gcol] = f2bf(v);
                } else if (EPI == 1) {
                    v = 0.5f * v * (1.0f + erff(v * 0.70710678118654752f));
                    Cb[(size_t)row * ldc + gcol] = f2bf(v);
                } else if (EPI == 2) {
                    Cf[(size_t)row * ldc + gcol] = R[(size_t)row * ldc + gcol] + v;
                } else {
                    Cf[(size_t)row * ldc + gcol] = v;
                }
            }
        }
    }
}

// ---------------------------------------------------------------- MFMA attention
// Block: 256 thr = 4 waves; one block per (b, h, 128-q-tile). Wave w owns 32 q rows.
// K-tiles of 64 keys staged in LDS (K row-major, V transposed), P via per-wave LDS.
__global__ __launch_bounds__(256)
void attn_mfma(const unsigned short* __restrict__ qkv, unsigned short* __restrict__ ob) {
    const int bq = blockIdx.x;      // 0..7
    const int h = blockIdx.y;       // 0..15
    const int b = blockIdx.z;       // 0..3
    const int tid = threadIdx.x, lane = tid & 63, w = tid >> 6;
    const int g = lane >> 4, lr = lane & 15;
    const int qg0 = bq * 128 + w * 32;

    __shared__ unsigned short Kt[64 * 72];
    __shared__ unsigned short Vt[64 * 72];          // transposed: Vt[d][k]
    __shared__ unsigned short Pl[4][32 * 72];
    unsigned short* Plw = Pl[w];

    // Q fragments (scale applied to S after MFMA)
    bfrag aq[2][2];
#pragma unroll
    for (int qs = 0; qs < 2; ++qs)
#pragma unroll
        for (int ks = 0; ks < 2; ++ks) {
            int row = qg0 + qs * 16 + lr;
            aq[qs][ks] = *reinterpret_cast<const bfrag*>(
                &qkv[(size_t)(b * Tt + row) * 3072 + h * 64 + ks * 32 + g * 8]);
        }

    float mrow[2][4], lrow[2][4], osc[2][4];
    f32x4 oacc[2][4];
#pragma unroll
    for (int qs = 0; qs < 2; ++qs)
#pragma unroll
        for (int r = 0; r < 4; ++r) { mrow[qs][r] = -3.0e38f; lrow[qs][r] = 0.f; }
#pragma unroll
    for (int qs = 0; qs < 2; ++qs)
#pragma unroll
        for (int dn = 0; dn < 4; ++dn)
#pragma unroll
            for (int r = 0; r < 4; ++r) oacc[qs][dn][r] = 0.f;

    const int ntile = 2 * bq + 2;
    for (int kt = 0; kt < ntile; ++kt) {
        {   // stage K rows + V transposed
            int row = tid >> 2, seg = tid & 3;
            const unsigned short* sk =
                &qkv[(size_t)(b * Tt + kt * 64 + row) * 3072 + Dm + h * 64 + seg * 16];
            bfrag k0 = *(const bfrag*)sk;
            bfrag k1 = *(const bfrag*)(sk + 8);
            *reinterpret_cast<bfrag*>(&Kt[row * 72 + seg * 16]) = k0;
            *reinterpret_cast<bfrag*>(&Kt[row * 72 + seg * 16 + 8]) = k1;
            const unsigned short* sv =
                &qkv[(size_t)(b * Tt + kt * 64 + row) * 3072 + 2 * Dm + h * 64 + seg * 16];
            bfrag v0 = *(const bfrag*)sv;
            bfrag v1 = *(const bfrag*)(sv + 8);
#pragma unroll
            for (int i = 0; i < 8; ++i) Vt[(seg * 16 + i) * 72 + row] = (unsigned short)v0[i];
#pragma unroll
            for (int i = 0; i < 8; ++i) Vt[(seg * 16 + 8 + i) * 72 + row] = (unsigned short)v1[i];
        }
        __syncthreads();

        bool active = (kt * 64 <= qg0 + 31);
        if (active) {
            // S = Q K^T  (32q x 64k)
            f32x4 s[2][4];
#pragma unroll
            for (int qs = 0; qs < 2; ++qs)
#pragma unroll
                for (int n = 0; n < 4; ++n)
#pragma unroll
                    for (int r = 0; r < 4; ++r) s[qs][n][r] = 0.f;
            bfrag bk[4][2];
#pragma unroll
            for (int n = 0; n < 4; ++n)
#pragma unroll
                for (int ks = 0; ks < 2; ++ks)
                    bk[n][ks] = *reinterpret_cast<const bfrag*>(
                        &Kt[(n * 16 + lr) * 72 + ks * 32 + g * 8]);
#pragma unroll
            for (int qs = 0; qs < 2; ++qs)
#pragma unroll
                for (int n = 0; n < 4; ++n)
#pragma unroll
                    for (int ks = 0; ks < 2; ++ks)
                        s[qs][n] = __builtin_amdgcn_mfma_f32_16x16x32_bf16(
                            aq[qs][ks], bk[n][ks], s[qs][n], 0, 0, 0);

            // online softmax per q row
            bool mayMask = (kt * 64 + 63 > qg0);
            float pv[2][4][4];
#pragma unroll
            for (int qs = 0; qs < 2; ++qs) {
#pragma unroll
                for (int r = 0; r < 4; ++r) {
                    int qrow = qg0 + qs * 16 + g * 4 + r;
                    float v[4];
#pragma unroll
                    for (int n = 0; n < 4; ++n) {
                        float sv = s[qs][n][r] * 0.125f;
                        if (mayMask && (kt * 64 + n * 16 + lr > qrow)) sv = -3.0e38f;
                        v[n] = sv;
                    }
                    float tmax = fmaxf(fmaxf(v[0], v[1]), fmaxf(v[2], v[3]));
                    tmax = fmaxf(tmax, __shfl_xor(tmax, 1));
                    tmax = fmaxf(tmax, __shfl_xor(tmax, 2));
                    tmax = fmaxf(tmax, __shfl_xor(tmax, 4));
                    tmax = fmaxf(tmax, __shfl_xor(tmax, 8));
                    float mold = mrow[qs][r];
                    float mnew = fmaxf(mold, tmax);
                    float scl = expf(mold - mnew);
                    float psum = 0.f;
#pragma unroll
                    for (int n = 0; n < 4; ++n) {
                        float p = expf(v[n] - mnew);
                        pv[qs][n][r] = p;
                        psum += p;
                    }
                    psum += __shfl_xor(psum, 1);
                    psum += __shfl_xor(psum, 2);
                    psum += __shfl_xor(psum, 4);
                    psum += __shfl_xor(psum, 8);
                    lrow[qs][r] = lrow[qs][r] * scl + psum;
                    mrow[qs][r] = mnew;
                    osc[qs][r] = scl;
                }
            }
            // rescale O
#pragma unroll
            for (int qs = 0; qs < 2; ++qs)
#pragma unroll
                for (int dn = 0; dn < 4; ++dn)
#pragma unroll
                    for (int r = 0; r < 4; ++r) oacc[qs][dn][r] *= osc[qs][r];
            // P -> LDS (bf16)
#pragma unroll
            for (int qs = 0; qs < 2; ++qs)
#pragma unroll
                for (int n = 0; n < 4; ++n)
#pragma unroll
                    for (int r = 0; r < 4; ++r)
                        Plw[(qs * 16 + g * 4 + r) * 72 + n * 16 + lr] = f2bf(pv[qs][n][r]);
            asm volatile("s_waitcnt lgkmcnt(0)" ::: "memory");
            // PV
            bfrag ap[2][2], bv[4][2];
#pragma unroll
            for (int qs = 0; qs < 2; ++qs)
#pragma unroll
                for (int ks = 0; ks < 2; ++ks)
                    ap[qs][ks] = *reinterpret_cast<const bfrag*>(
                        &Plw[(qs * 16 + lr) * 72 + ks * 32 + g * 8]);
#pragma unroll
            for (int dn = 0; dn < 4; ++dn)
#pragma unroll
                for (int ks = 0; ks < 2; ++ks)
                    bv[dn][ks] = *reinterpret_cast<const bfrag*>(
                        &Vt[(dn * 16 + lr) * 72 + ks * 32 + g * 8]);
#pragma unroll
            for (int qs = 0; qs < 2; ++qs)
#pragma unroll
                for (int dn = 0; dn < 4; ++dn)
#pragma unroll
                    for (int ks = 0; ks < 2; ++ks)
                        oacc[qs][dn] = __builtin_amdgcn_mfma_f32_16x16x32_bf16(
                            ap[qs][ks], bv[dn][ks], oacc[qs][dn], 0, 0, 0);
        }
        __syncthreads();
    }

    // write O
#pragma unroll
    for (int qs = 0; qs < 2; ++qs)
#pragma unroll
        for (int r = 0; r < 4; ++r) {
            float rinv = 1.0f / lrow[qs][r];
            int qrow = qg0 + qs * 16 + g * 4 + r;
#pragma unroll
            for (int dn = 0; dn < 4; ++dn)
                ob[(size_t)(b * Tt + qrow) * Dm + h * 64 + dn * 16 + lr] =
                    f2bf(oacc[qs][dn][r] * rinv);
        }
}

// ---------------------------------------------------------------- loss
__global__ __launch_bounds__(256)
void loss_row_kernel(float* __restrict__ nll, const float* __restrict__ logits,
                     const int* __restrict__ targets) {
    int row = blockIdx.x;
    int tid = threadIdx.x;
    const float* lr = logits + (size_t)row * Vv;
    __shared__ float red[256];
    float lmax = -INFINITY;
    for (int j = tid; j < Vv; j += 256) lmax = fmaxf(lmax, lr[j]);
    red[tid] = lmax;
    __syncthreads();
    for (int s = 128; s > 0; s >>= 1) {
        if (tid < s) red[tid] = fmaxf(red[tid], red[tid + s]);
        __syncthreads();
    }
    float m = red[0];
    __syncthreads();
    float lsum = 0.f;
    for (int j = tid; j < Vv; j += 256) lsum += expf(lr[j] - m);
    red[tid] = lsum;
    __syncthreads();
    for (int s = 128; s > 0; s >>= 1) {
        if (tid < s) red[tid] += red[tid + s];
        __syncthreads();
    }
    if (tid == 0) {
        float lse = m + logf(red[0]);
        nll[row] = lse - lr[targets[row]];
    }
}

__global__ __launch_bounds__(256)
void loss_reduce_kernel(float* __restrict__ loss, const float* __restrict__ nll) {
    int tid = threadIdx.x;
    __shared__ float red[256];
    float s = 0.f;
    for (int j = tid; j < Mrows; j += 256) s += nll[j];
    __syncthreads();
    red[tid] = s;
    __syncthreads();
    for (int st = 128; st > 0; st >>= 1) {
        if (tid < st) red[tid] += red[tid + st];
        __syncthreads();
    }
    if (tid == 0) *loss = red[0] * (1.0f / Mrows);
}

// ---------------------------------------------------------------- launch
extern "C" void kernel_launch(void* const* d_in, const int* in_sizes, int n_in,
                              void* d_out, int out_size, void* d_ws, size_t ws_size,
                              hipStream_t stream) {
    const int* idx = (const int*)d_in[0];
    const int* targets = (const int*)d_in[1];
    const float* wte = (const float*)d_in[2];
    const float* wpe = (const float*)d_in[3];
    const float* ln1_w = (const float*)d_in[4];
    const float* ln1_b = (const float*)d_in[5];
    const float* qkv_w = (const float*)d_in[6];
    const float* qkv_b = (const float*)d_in[7];
    const float* o_w = (const float*)d_in[8];
    const float* o_b = (const float*)d_in[9];
    const float* ln2_w = (const float*)d_in[10];
    const float* ln2_b = (const float*)d_in[11];
    const float* up_w = (const float*)d_in[12];
    const float* up_b = (const float*)d_in[13];
    const float* down_w = (const float*)d_in[14];
    const float* down_b = (const float*)d_in[15];
    const float* lnf_w = (const float*)d_in[16];
    const float* lnf_b = (const float*)d_in[17];
    const float* lm_b = (const float*)d_in[18];

    float* logits = (float*)d_out;
    char* ws = (char*)d_ws;
    const size_t MB = 1 << 20;
    float* x            = (float*)(ws);                       // 16 MB
    unsigned short* y   = (unsigned short*)(ws + 16 * MB);    // 8 MB
    unsigned short* qkv = (unsigned short*)(ws + 24 * MB);    // 24 MB
    unsigned short* ob  = (unsigned short*)(ws + 48 * MB);    // 8 MB
    unsigned short* up  = (unsigned short*)(ws + 56 * MB);    // 32 MB
    unsigned short* wTq = (unsigned short*)(ws + 88 * MB);    // 6.3 MB
    unsigned short* wTo = (unsigned short*)(ws + 96 * MB);    // 2.1 MB
    unsigned short* wTu = (unsigned short*)(ws + 100 * MB);   // 8.4 MB
    unsigned short* wTd = (unsigned short*)(ws + 112 * MB);   // 8.4 MB
    float* nll          = (float*)(ws + 124 * MB);            // 16 KB
    unsigned short* wbf = (unsigned short*)(ws + 88 * MB);    // lm chunks (26.2 MB, reuses wT*)

    embed_kernel<<<Mrows, 256, 0, stream>>>(x, wte, wpe, idx);

    for (int l = 0; l < Ll; ++l) {
        ln_kernel<<<Mrows, 256, 0, stream>>>(y, x, ln1_w + l * Dm, ln1_b + l * Dm);
        transpose_k<<<dim3(3 * Dm / 32, Dm / 32), 256, 0, stream>>>(
            wTq, qkv_w + (size_t)l * Dm * 3 * Dm, Dm, 3 * Dm);
        gemm_mfma<0, 0><<<dim3(Mrows / 128, 3 * Dm / 128), 256, 0, stream>>>(
            y, wTq, qkv_b + (size_t)l * 3 * Dm, nullptr, qkv, Mrows, 3 * Dm, Dm, 3 * Dm, 0);
        attn_mfma<<<dim3(8, Hh, Bb), 256, 0, stream>>>(qkv, ob);
        transpose_k<<<dim3(Dm / 32, Dm / 32), 256, 0, stream>>>(
            wTo, o_w + (size_t)l * Dm * Dm, Dm, Dm);
        gemm_mfma<2, 0><<<dim3(Mrows / 128, Dm / 128), 256, 0, stream>>>(
            ob, wTo, o_b + (size_t)l * Dm, x, x, Mrows, Dm, Dm, Dm, 0);
        ln_kernel<<<Mrows, 256, 0, stream>>>(y, x, ln2_w + l * Dm, ln2_b + l * Dm);
        transpose_k<<<dim3(4 * Dm / 32, Dm / 32), 256, 0, stream>>>(
            wTu, up_w + (size_t)l * Dm * 4 * Dm, Dm, 4 * Dm);
        gemm_mfma<1, 0><<<dim3(Mrows / 128, 4 * Dm / 128), 256, 0, stream>>>(
            y, wTu, up_b + (size_t)l * 4 * Dm, nullptr, up, Mrows, 4 * Dm, Dm, 4 * Dm, 0);
        transpose_k<<<dim3(Dm / 32, 4 * Dm / 32), 256, 0, stream>>>(
            wTd, down_w + (size_t)l * 4 * Dm * Dm, 4 * Dm, Dm);
        gemm_mfma<2, 0><<<dim3(Mrows / 128, Dm / 128), 256, 0, stream>>>(
            up, wTd, down_b + (size_t)l * Dm, x, x, Mrows, Dm, 4 * Dm, Dm, 0);
    }

    ln_kernel<<<Mrows, 256, 0, stream>>>(y, x, lnf_w, lnf_b);

    const int CH = 12800;
    for (int c0 = 0; c0 < Vv; c0 += CH) {
        int nv = (Vv - c0 < CH) ? (Vv - c0) : CH;
        cvt_rows<<<nv, 128, 0, stream>>>(wbf, wte + (size_t)c0 * Dm);
        gemm_mfma<3, 1><<<dim3(Mrows / 128, (nv + 127) / 128), 256, 0, stream>>>(
            y, wbf, lm_b, nullptr, logits, Mrows, nv, Dm, Vv, c0);
    }

    loss_row_kernel<<<Mrows, 256, 0, stream>>>(nll, logits, targets);
    loss_reduce_kernel<<<1, 256, 0, stream>>>(logits + (size_t)Mrows * Vv, nll);
}

// Round 4
// 5338.354 us; speedup vs baseline: 8.5287x; 1.0516x over previous
//
#include <hip/hip_runtime.h>
#include <hip/hip_bf16.h>
#include <math.h>

typedef __attribute__((ext_vector_type(8))) short bfrag;   // 8 bf16 (4 VGPRs)
typedef __attribute__((ext_vector_type(4))) float f32x4;

static constexpr int Dm = 1024, Hh = 16, HD = 64, Ll = 12, Tt = 1024, Bb = 4;
static constexpr int Vv = 50257, Mrows = 4096;

__device__ inline unsigned short f2bf(float f) {  // RNE f32->bf16
    unsigned u = __float_as_uint(f);
    u += 0x7fffu + ((u >> 16) & 1u);
    return (unsigned short)(u >> 16);
}
__device__ inline float bf2f(unsigned short s) {
    return __uint_as_float(((unsigned)s) << 16);
}

__device__ inline void gload16(const unsigned short* g, unsigned short* l) {
    __builtin_amdgcn_global_load_lds(
        (const __attribute__((address_space(1))) void*)g,
        (__attribute__((address_space(3))) void*)l, 16, 0, 0);
}

// ---------------------------------------------------------------- embed (f32)
__global__ __launch_bounds__(256)
void embed_kernel(float* __restrict__ x, const float* __restrict__ wte,
                  const float* __restrict__ wpe, const int* __restrict__ idx) {
    int row = blockIdx.x;
    int t = row & (Tt - 1);
    int id = idx[row];
    int c = threadIdx.x * 4;
    float4 a = *reinterpret_cast<const float4*>(&wte[(size_t)id * Dm + c]);
    float4 p = *reinterpret_cast<const float4*>(&wpe[(size_t)t * Dm + c]);
    float4 o;
    o.x = a.x + p.x; o.y = a.y + p.y; o.z = a.z + p.z; o.w = a.w + p.w;
    *reinterpret_cast<float4*>(&x[(size_t)row * Dm + c]) = o;
}

// ---------------------------------------------------------------- layernorm: f32 in, bf16 out
// single-pass (sum, sumsq) via wave shuffles; 1 barrier.
__global__ __launch_bounds__(256)
void ln_kernel(unsigned short* __restrict__ y, const float* __restrict__ x,
               const float* __restrict__ w, const float* __restrict__ b) {
    int row = blockIdx.x;
    int tid = threadIdx.x;
    int lane = tid & 63, wv = tid >> 6;
    const float* xr = x + (size_t)row * Dm;
    float4 v = *reinterpret_cast<const float4*>(&xr[tid * 4]);
    float s1 = v.x + v.y + v.z + v.w;
    float s2 = v.x * v.x + v.y * v.y + v.z * v.z + v.w * v.w;
#pragma unroll
    for (int off = 1; off < 64; off <<= 1) {
        s1 += __shfl_xor(s1, off);
        s2 += __shfl_xor(s2, off);
    }
    __shared__ float r1[4], r2[4];
    if (lane == 0) { r1[wv] = s1; r2[wv] = s2; }
    __syncthreads();
    s1 = r1[0] + r1[1] + r1[2] + r1[3];
    s2 = r2[0] + r2[1] + r2[2] + r2[3];
    float mean = s1 * (1.0f / Dm);
    float var = s2 * (1.0f / Dm) - mean * mean;
    float rstd = rsqrtf(var + 1e-5f);
    float4 wvv = *reinterpret_cast<const float4*>(&w[tid * 4]);
    float4 bv = *reinterpret_cast<const float4*>(&b[tid * 4]);
    ushort4 o;
    o.x = f2bf((v.x - mean) * rstd * wvv.x + bv.x);
    o.y = f2bf((v.y - mean) * rstd * wvv.y + bv.y);
    o.z = f2bf((v.z - mean) * rstd * wvv.z + bv.z);
    o.w = f2bf((v.w - mean) * rstd * wvv.w + bv.w);
    *reinterpret_cast<ushort4*>(&y[(size_t)row * Dm + tid * 4]) = o;
}

// ------------------------------------------------- fused per-layer weight transpose
// All four weights of one layer: w[K][N] f32 -> wT[N][K] bf16.
__global__ __launch_bounds__(256)
void transpose_layer(const float* __restrict__ qw, const float* __restrict__ ow,
                     const float* __restrict__ uw, const float* __restrict__ dw,
                     unsigned short* __restrict__ wTq, unsigned short* __restrict__ wTo,
                     unsigned short* __restrict__ wTu, unsigned short* __restrict__ wTd) {
    __shared__ float t[32][33];
    int tb = blockIdx.x;
    const float* src; unsigned short* dst; int K, N, nx, base;
    if (tb < 3072)      { src = qw; dst = wTq; K = 1024; N = 3072; nx = 96;  base = 0; }
    else if (tb < 4096) { src = ow; dst = wTo; K = 1024; N = 1024; nx = 32;  base = 3072; }
    else if (tb < 8192) { src = uw; dst = wTu; K = 1024; N = 4096; nx = 128; base = 4096; }
    else                { src = dw; dst = wTd; K = 4096; N = 1024; nx = 32;  base = 8192; }
    int tt = tb - base;
    int n0 = (tt % nx) * 32, k0 = (tt / nx) * 32;
    int tid = threadIdx.x;
    int r = tid >> 3, c4 = (tid & 7) * 4;
    float4 v = *reinterpret_cast<const float4*>(&src[(size_t)(k0 + r) * N + n0 + c4]);
    t[r][c4] = v.x; t[r][c4 + 1] = v.y; t[r][c4 + 2] = v.z; t[r][c4 + 3] = v.w;
    __syncthreads();
    int nr = tid >> 3, kc = (tid & 7) * 4;
    ushort4 o;
    o.x = f2bf(t[kc][nr]);
    o.y = f2bf(t[kc + 1][nr]);
    o.z = f2bf(t[kc + 2][nr]);
    o.w = f2bf(t[kc + 3][nr]);
    *reinterpret_cast<ushort4*>(&dst[(size_t)(n0 + nr) * K + k0 + kc]) = o;
}

// ------------------------------------------------- f32 rows -> bf16 rows (lm_head chunks)
__global__ __launch_bounds__(128)
void cvt_rows(unsigned short* __restrict__ dst, const float* __restrict__ src) {
    int row = blockIdx.x;
    int t = threadIdx.x;
    const float* s = src + (size_t)row * Dm + t * 8;
    float4 f0 = *reinterpret_cast<const float4*>(s);
    float4 f1 = *reinterpret_cast<const float4*>(s + 4);
    ushort4 o0, o1;
    o0.x = f2bf(f0.x); o0.y = f2bf(f0.y); o0.z = f2bf(f0.z); o0.w = f2bf(f0.w);
    o1.x = f2bf(f1.x); o1.y = f2bf(f1.y); o1.z = f2bf(f1.z); o1.w = f2bf(f1.w);
    unsigned short* d = dst + (size_t)row * Dm + t * 8;
    *reinterpret_cast<ushort4*>(d) = o0;
    *reinterpret_cast<ushort4*>(d + 4) = o1;
}

// ---------------------------------------------------------------- MFMA GEMM
// 128x128 tile, BK=64, global_load_lds staging with XOR granule swizzle,
// XCD-aware block swizzle. C[M,*] = A[M,K]bf16 @ B[Nv,K]^T bf16 + bias.
// EPI 0: C bf16. 1: C bf16 gelu. 2: C f32 = R+acc+bias. 3: C f32 (guard col<Nv).
template<int EPI, int GN>
__global__ __launch_bounds__(256)
void gemm_mfma(const unsigned short* __restrict__ A, const unsigned short* __restrict__ B,
               const float* __restrict__ bias, const float* __restrict__ R,
               void* __restrict__ Cp, int M, int Nv, int K, int ldc, int ncol) {
    __shared__ unsigned short As[128 * 64];
    __shared__ unsigned short Bs[128 * 64];
    const int tid = threadIdx.x;
    const int lane = tid & 63, wid = tid >> 6;
    // XCD-aware bijective swizzle (m204) over linearized grid
    const int gx = gridDim.x;
    int flat = blockIdx.y * gx + blockIdx.x;
    int nwg = gx * gridDim.y;
    {
        int q = nwg >> 3, rr = nwg & 7;
        int xcd = flat & 7, pos = flat >> 3;
        flat = ((xcd < rr) ? (xcd * (q + 1)) : (rr * (q + 1) + (xcd - rr) * q)) + pos;
    }
    const int bm = (flat % gx) * 128;
    const int bn = (flat / gx) * 128;
    const int wr = wid >> 1, wc = wid & 1;
    const int g = lane >> 4, lr = lane & 15;
    const int l8 = lane >> 3;                 // 0..7  (row-in-segment)
    const int k8 = (lane & 7) ^ l8;           // swizzled source granule

    f32x4 acc[4][4];
#pragma unroll
    for (int i = 0; i < 4; ++i)
#pragma unroll
        for (int j = 0; j < 4; ++j)
#pragma unroll
            for (int r = 0; r < 4; ++r) acc[i][j][r] = 0.f;

    for (int k0 = 0; k0 < K; k0 += 64) {
        // 32 segments of 8 rows x 64k; wave wid stages segments wid*8..wid*8+7
#pragma unroll
        for (int jj = 0; jj < 8; ++jj) {
            int j = wid * 8 + jj;
            if (j < 16) {
                int row = j * 8 + l8;
                gload16(&A[(size_t)(bm + row) * K + k0 + k8 * 8], &As[j * 512]);
            } else {
                int j16 = j - 16;
                int row = j16 * 8 + l8;
                int grow = bn + row;
                if (GN) grow = (grow < Nv) ? grow : (Nv - 1);
                gload16(&B[(size_t)grow * K + k0 + k8 * 8], &Bs[j16 * 512]);
            }
        }
        __syncthreads();
#pragma unroll
        for (int ks = 0; ks < 2; ++ks) {
            bfrag af[4], bfr[4];
#pragma unroll
            for (int i = 0; i < 4; ++i) {
                int ra = wr * 64 + i * 16 + lr;
                af[i] = *reinterpret_cast<const bfrag*>(
                    &As[ra * 64 + ((((ks << 2) | g) ^ (ra & 7)) * 8)]);
                int rb = wc * 64 + i * 16 + lr;
                bfr[i] = *reinterpret_cast<const bfrag*>(
                    &Bs[rb * 64 + ((((ks << 2) | g) ^ (rb & 7)) * 8)]);
            }
#pragma unroll
            for (int mi = 0; mi < 4; ++mi)
#pragma unroll
                for (int ni = 0; ni < 4; ++ni)
                    acc[mi][ni] = __builtin_amdgcn_mfma_f32_16x16x32_bf16(
                        af[mi], bfr[ni], acc[mi][ni], 0, 0, 0);
        }
        __syncthreads();
    }

    unsigned short* Cb = (unsigned short*)Cp;
    float* Cf = (float*)Cp;
#pragma unroll
    for (int ni = 0; ni < 4; ++ni) {
        int col = bn + wc * 64 + ni * 16 + lr;
        if (GN && col >= Nv) continue;
        int gcol = ncol + col;
        float bi = bias[gcol];
#pragma unroll
        for (int mi = 0; mi < 4; ++mi) {
            int row0 = bm + wr * 64 + mi * 16 + g * 4;
#pragma unroll
            for (int r = 0; r < 4; ++r) {
                int row = row0 + r;
                float v = acc[mi][ni][r] + bi;
                if (EPI == 0) {
                    Cb[(size_t)row * ldc + gcol] = f2bf(v);
                } else if (EPI == 1) {
                    v = 0.5f * v * (1.0f + erff(v * 0.70710678118654752f));
                    Cb[(size_t)row * ldc + gcol] = f2bf(v);
                } else if (EPI == 2) {
                    Cf[(size_t)row * ldc + gcol] = R[(size_t)row * ldc + gcol] + v;
                } else {
                    Cf[(size_t)row * ldc + gcol] = v;
                }
            }
        }
    }
}

// ---------------------------------------------------------------- MFMA attention
// 4 waves; one block per (b, h, 128-q-tile); wave owns 32 q rows.
__global__ __launch_bounds__(256)
void attn_mfma(const unsigned short* __restrict__ qkv, unsigned short* __restrict__ ob) {
    const int bq = blockIdx.x;
    const int h = blockIdx.y;
    const int b = blockIdx.z;
    const int tid = threadIdx.x, lane = tid & 63, w = tid >> 6;
    const int g = lane >> 4, lr = lane & 15;
    const int qg0 = bq * 128 + w * 32;

    __shared__ unsigned short Kt[64 * 72];
    __shared__ unsigned short Vt[64 * 72];          // transposed: Vt[d][k]
    __shared__ unsigned short Pl[4][32 * 72];
    unsigned short* Plw = Pl[w];

    bfrag aq[2][2];
#pragma unroll
    for (int qs = 0; qs < 2; ++qs)
#pragma unroll
        for (int ks = 0; ks < 2; ++ks) {
            int row = qg0 + qs * 16 + lr;
            aq[qs][ks] = *reinterpret_cast<const bfrag*>(
                &qkv[(size_t)(b * Tt + row) * 3072 + h * 64 + ks * 32 + g * 8]);
        }

    float mrow[2][4], lrow[2][4], osc[2][4];
    f32x4 oacc[2][4];
#pragma unroll
    for (int qs = 0; qs < 2; ++qs)
#pragma unroll
        for (int r = 0; r < 4; ++r) { mrow[qs][r] = -3.0e38f; lrow[qs][r] = 0.f; }
#pragma unroll
    for (int qs = 0; qs < 2; ++qs)
#pragma unroll
        for (int dn = 0; dn < 4; ++dn)
#pragma unroll
            for (int r = 0; r < 4; ++r) oacc[qs][dn][r] = 0.f;

    const int ntile = 2 * bq + 2;
    for (int kt = 0; kt < ntile; ++kt) {
        {   // stage K rows (b128) + V transposed (seg-rotated scalar writes, bank-even)
            int row = tid >> 2, seg = tid & 3;
            const unsigned short* sk =
                &qkv[(size_t)(b * Tt + kt * 64 + row) * 3072 + Dm + h * 64 + seg * 16];
            bfrag kv0 = *(const bfrag*)sk;
            bfrag kv1 = *(const bfrag*)(sk + 8);
            *reinterpret_cast<bfrag*>(&Kt[row * 72 + seg * 16]) = kv0;
            *reinterpret_cast<bfrag*>(&Kt[row * 72 + seg * 16 + 8]) = kv1;
            const uint4* sv = reinterpret_cast<const uint4*>(
                &qkv[(size_t)(b * Tt + kt * 64 + row) * 3072 + 2 * Dm + h * 64 + seg * 16]);
            uint4 u0 = sv[0], u1 = sv[1];
            uint4 a, r0, r1;
            a.x = (seg & 1) ? u0.y : u0.x; a.y = (seg & 1) ? u0.z : u0.y;
            a.z = (seg & 1) ? u0.w : u0.z; a.w = (seg & 1) ? u0.x : u0.w;
            r0.x = (seg & 2) ? a.z : a.x; r0.y = (seg & 2) ? a.w : a.y;
            r0.z = (seg & 2) ? a.x : a.z; r0.w = (seg & 2) ? a.y : a.w;
            a.x = (seg & 1) ? u1.y : u1.x; a.y = (seg & 1) ? u1.z : u1.y;
            a.z = (seg & 1) ? u1.w : u1.z; a.w = (seg & 1) ? u1.x : u1.w;
            r1.x = (seg & 2) ? a.z : a.x; r1.y = (seg & 2) ? a.w : a.y;
            r1.z = (seg & 2) ? a.x : a.z; r1.w = (seg & 2) ? a.y : a.w;
            unsigned w0[4] = {r0.x, r0.y, r0.z, r0.w};
            unsigned w1[4] = {r1.x, r1.y, r1.z, r1.w};
#pragma unroll
            for (int i = 0; i < 8; ++i) {
                int j = (i + 2 * seg) & 7;
                unsigned ww = w0[i >> 1];
                unsigned short val = (i & 1) ? (unsigned short)(ww >> 16)
                                             : (unsigned short)(ww & 0xffff);
                Vt[(seg * 16 + j) * 72 + row] = val;
            }
#pragma unroll
            for (int i = 0; i < 8; ++i) {
                int j = (i + 2 * seg) & 7;
                unsigned ww = w1[i >> 1];
                unsigned short val = (i & 1) ? (unsigned short)(ww >> 16)
                                             : (unsigned short)(ww & 0xffff);
                Vt[(seg * 16 + 8 + j) * 72 + row] = val;
            }
        }
        __syncthreads();

        bool active = (kt * 64 <= qg0 + 31);
        if (active) {
            f32x4 s[2][4];
#pragma unroll
            for (int qs = 0; qs < 2; ++qs)
#pragma unroll
                for (int n = 0; n < 4; ++n)
#pragma unroll
                    for (int r = 0; r < 4; ++r) s[qs][n][r] = 0.f;
            bfrag bk[4][2];
#pragma unroll
            for (int n = 0; n < 4; ++n)
#pragma unroll
                for (int ks = 0; ks < 2; ++ks)
                    bk[n][ks] = *reinterpret_cast<const bfrag*>(
                        &Kt[(n * 16 + lr) * 72 + ks * 32 + g * 8]);
#pragma unroll
            for (int qs = 0; qs < 2; ++qs)
#pragma unroll
                for (int n = 0; n < 4; ++n)
#pragma unroll
                    for (int ks = 0; ks < 2; ++ks)
                        s[qs][n] = __builtin_amdgcn_mfma_f32_16x16x32_bf16(
                            aq[qs][ks], bk[n][ks], s[qs][n], 0, 0, 0);

            bool mayMask = (kt * 64 + 63 > qg0);
            float pv[2][4][4];
#pragma unroll
            for (int qs = 0; qs < 2; ++qs) {
#pragma unroll
                for (int r = 0; r < 4; ++r) {
                    int qrow = qg0 + qs * 16 + g * 4 + r;
                    float v[4];
#pragma unroll
                    for (int n = 0; n < 4; ++n) {
                        float sv = s[qs][n][r] * 0.125f;
                        if (mayMask && (kt * 64 + n * 16 + lr > qrow)) sv = -3.0e38f;
                        v[n] = sv;
                    }
                    float tmax = fmaxf(fmaxf(v[0], v[1]), fmaxf(v[2], v[3]));
                    tmax = fmaxf(tmax, __shfl_xor(tmax, 1));
                    tmax = fmaxf(tmax, __shfl_xor(tmax, 2));
                    tmax = fmaxf(tmax, __shfl_xor(tmax, 4));
                    tmax = fmaxf(tmax, __shfl_xor(tmax, 8));
                    float mold = mrow[qs][r];
                    float mnew = fmaxf(mold, tmax);
                    float scl = expf(mold - mnew);
                    float psum = 0.f;
#pragma unroll
                    for (int n = 0; n < 4; ++n) {
                        float p = expf(v[n] - mnew);
                        pv[qs][n][r] = p;
                        psum += p;
                    }
                    psum += __shfl_xor(psum, 1);
                    psum += __shfl_xor(psum, 2);
                    psum += __shfl_xor(psum, 4);
                    psum += __shfl_xor(psum, 8);
                    lrow[qs][r] = lrow[qs][r] * scl + psum;
                    mrow[qs][r] = mnew;
                    osc[qs][r] = scl;
                }
            }
#pragma unroll
            for (int qs = 0; qs < 2; ++qs)
#pragma unroll
                for (int dn = 0; dn < 4; ++dn)
#pragma unroll
                    for (int r = 0; r < 4; ++r) oacc[qs][dn][r] *= osc[qs][r];
#pragma unroll
            for (int qs = 0; qs < 2; ++qs)
#pragma unroll
                for (int n = 0; n < 4; ++n)
#pragma unroll
                    for (int r = 0; r < 4; ++r)
                        Plw[(qs * 16 + g * 4 + r) * 72 + n * 16 + lr] = f2bf(pv[qs][n][r]);
            asm volatile("s_waitcnt lgkmcnt(0)" ::: "memory");
            bfrag ap[2][2], bv[4][2];
#pragma unroll
            for (int qs = 0; qs < 2; ++qs)
#pragma unroll
                for (int ks = 0; ks < 2; ++ks)
                    ap[qs][ks] = *reinterpret_cast<const bfrag*>(
                        &Plw[(qs * 16 + lr) * 72 + ks * 32 + g * 8]);
#pragma unroll
            for (int dn = 0; dn < 4; ++dn)
#pragma unroll
                for (int ks = 0; ks < 2; ++ks)
                    bv[dn][ks] = *reinterpret_cast<const bfrag*>(
                        &Vt[(dn * 16 + lr) * 72 + ks * 32 + g * 8]);
#pragma unroll
            for (int qs = 0; qs < 2; ++qs)
#pragma unroll
                for (int dn = 0; dn < 4; ++dn)
#pragma unroll
                    for (int ks = 0; ks < 2; ++ks)
                        oacc[qs][dn] = __builtin_amdgcn_mfma_f32_16x16x32_bf16(
                            ap[qs][ks], bv[dn][ks], oacc[qs][dn], 0, 0, 0);
        }
        __syncthreads();
    }

#pragma unroll
    for (int qs = 0; qs < 2; ++qs)
#pragma unroll
        for (int r = 0; r < 4; ++r) {
            float rinv = 1.0f / lrow[qs][r];
            int qrow = qg0 + qs * 16 + g * 4 + r;
#pragma unroll
            for (int dn = 0; dn < 4; ++dn)
                ob[(size_t)(b * Tt + qrow) * Dm + h * 64 + dn * 16 + lr] =
                    f2bf(oacc[qs][dn][r] * rinv);
        }
}

// ---------------------------------------------------------------- loss
__global__ __launch_bounds__(256)
void loss_row_kernel(float* __restrict__ nll, const float* __restrict__ logits,
                     const int* __restrict__ targets) {
    int row = blockIdx.x;
    int tid = threadIdx.x;
    const float* lr = logits + (size_t)row * Vv;
    __shared__ float red[256];
    float lmax = -INFINITY;
    for (int j = tid; j < Vv; j += 256) lmax = fmaxf(lmax, lr[j]);
    red[tid] = lmax;
    __syncthreads();
    for (int s = 128; s > 0; s >>= 1) {
        if (tid < s) red[tid] = fmaxf(red[tid], red[tid + s]);
        __syncthreads();
    }
    float m = red[0];
    __syncthreads();
    float lsum = 0.f;
    for (int j = tid; j < Vv; j += 256) lsum += expf(lr[j] - m);
    red[tid] = lsum;
    __syncthreads();
    for (int s = 128; s > 0; s >>= 1) {
        if (tid < s) red[tid] += red[tid + s];
        __syncthreads();
    }
    if (tid == 0) {
        float lse = m + logf(red[0]);
        nll[row] = lse - lr[targets[row]];
    }
}

__global__ __launch_bounds__(256)
void loss_reduce_kernel(float* __restrict__ loss, const float* __restrict__ nll) {
    int tid = threadIdx.x;
    __shared__ float red[256];
    float s = 0.f;
    for (int j = tid; j < Mrows; j += 256) s += nll[j];
    red[tid] = s;
    __syncthreads();
    for (int st = 128; st > 0; st >>= 1) {
        if (tid < st) red[tid] += red[tid + st];
        __syncthreads();
    }
    if (tid == 0) *loss = red[0] * (1.0f / Mrows);
}

// ---------------------------------------------------------------- launch
extern "C" void kernel_launch(void* const* d_in, const int* in_sizes, int n_in,
                              void* d_out, int out_size, void* d_ws, size_t ws_size,
                              hipStream_t stream) {
    const int* idx = (const int*)d_in[0];
    const int* targets = (const int*)d_in[1];
    const float* wte = (const float*)d_in[2];
    const float* wpe = (const float*)d_in[3];
    const float* ln1_w = (const float*)d_in[4];
    const float* ln1_b = (const float*)d_in[5];
    const float* qkv_w = (const float*)d_in[6];
    const float* qkv_b = (const float*)d_in[7];
    const float* o_w = (const float*)d_in[8];
    const float* o_b = (const float*)d_in[9];
    const float* ln2_w = (const float*)d_in[10];
    const float* ln2_b = (const float*)d_in[11];
    const float* up_w = (const float*)d_in[12];
    const float* up_b = (const float*)d_in[13];
    const float* down_w = (const float*)d_in[14];
    const float* down_b = (const float*)d_in[15];
    const float* lnf_w = (const float*)d_in[16];
    const float* lnf_b = (const float*)d_in[17];
    const float* lm_b = (const float*)d_in[18];

    float* logits = (float*)d_out;
    char* ws = (char*)d_ws;
    const size_t MB = 1 << 20;
    float* x            = (float*)(ws);                       // 16 MB
    unsigned short* y   = (unsigned short*)(ws + 16 * MB);    // 8 MB
    unsigned short* qkv = (unsigned short*)(ws + 24 * MB);    // 24 MB
    unsigned short* ob  = (unsigned short*)(ws + 48 * MB);    // 8 MB
    unsigned short* up  = (unsigned short*)(ws + 56 * MB);    // 32 MB
    unsigned short* wTq = (unsigned short*)(ws + 88 * MB);    // 6.3 MB
    unsigned short* wTo = (unsigned short*)(ws + 96 * MB);    // 2.1 MB
    unsigned short* wTu = (unsigned short*)(ws + 100 * MB);   // 8.4 MB
    unsigned short* wTd = (unsigned short*)(ws + 112 * MB);   // 8.4 MB
    float* nll          = (float*)(ws + 124 * MB);            // 16 KB
    unsigned short* wbf = (unsigned short*)(ws + 88 * MB);    // lm chunks (reuses wT*)

    embed_kernel<<<Mrows, 256, 0, stream>>>(x, wte, wpe, idx);

    for (int l = 0; l < Ll; ++l) {
        ln_kernel<<<Mrows, 256, 0, stream>>>(y, x, ln1_w + l * Dm, ln1_b + l * Dm);
        transpose_layer<<<12288, 256, 0, stream>>>(
            qkv_w + (size_t)l * Dm * 3 * Dm, o_w + (size_t)l * Dm * Dm,
            up_w + (size_t)l * Dm * 4 * Dm, down_w + (size_t)l * 4 * Dm * Dm,
            wTq, wTo, wTu, wTd);
        gemm_mfma<0, 0><<<dim3(Mrows / 128, 3 * Dm / 128), 256, 0, stream>>>(
            y, wTq, qkv_b + (size_t)l * 3 * Dm, nullptr, qkv, Mrows, 3 * Dm, Dm, 3 * Dm, 0);
        attn_mfma<<<dim3(8, Hh, Bb), 256, 0, stream>>>(qkv, ob);
        gemm_mfma<2, 0><<<dim3(Mrows / 128, Dm / 128), 256, 0, stream>>>(
            ob, wTo, o_b + (size_t)l * Dm, x, x, Mrows, Dm, Dm, Dm, 0);
        ln_kernel<<<Mrows, 256, 0, stream>>>(y, x, ln2_w + l * Dm, ln2_b + l * Dm);
        gemm_mfma<1, 0><<<dim3(Mrows / 128, 4 * Dm / 128), 256, 0, stream>>>(
            y, wTu, up_b + (size_t)l * 4 * Dm, nullptr, up, Mrows, 4 * Dm, Dm, 4 * Dm, 0);
        gemm_mfma<2, 0><<<dim3(Mrows / 128, Dm / 128), 256, 0, stream>>>(
            up, wTd, down_b + (size_t)l * Dm, x, x, Mrows, Dm, 4 * Dm, Dm, 0);
    }

    ln_kernel<<<Mrows, 256, 0, stream>>>(y, x, lnf_w, lnf_b);

    const int CH = 12800;
    for (int c0 = 0; c0 < Vv; c0 += CH) {
        int nv = (Vv - c0 < CH) ? (Vv - c0) : CH;
        cvt_rows<<<nv, 128, 0, stream>>>(wbf, wte + (size_t)c0 * Dm);
        gemm_mfma<3, 1><<<dim3(Mrows / 128, (nv + 127) / 128), 256, 0, stream>>>(
            y, wbf, lm_b, nullptr, logits, Mrows, nv, Dm, Vv, c0);
    }

    loss_row_kernel<<<Mrows, 256, 0, stream>>>(nll, logits, targets);
    loss_reduce_kernel<<<1, 256, 0, stream>>>(logits + (size_t)Mrows * Vv, nll);
}

// Round 5
// 5222.541 us; speedup vs baseline: 8.7179x; 1.0222x over previous
//
#include <hip/hip_runtime.h>
#include <hip/hip_bf16.h>
#include <math.h>

typedef __attribute__((ext_vector_type(8))) short bfrag;   // 8 bf16 (4 VGPRs)
typedef __attribute__((ext_vector_type(4))) float f32x4;

static constexpr int Dm = 1024, Hh = 16, HD = 64, Ll = 12, Tt = 1024, Bb = 4;
static constexpr int Vv = 50257, Mrows = 4096;

__device__ inline unsigned short f2bf(float f) {  // RNE f32->bf16
    unsigned u = __float_as_uint(f);
    u += 0x7fffu + ((u >> 16) & 1u);
    return (unsigned short)(u >> 16);
}
__device__ inline float bf2f(unsigned short s) {
    return __uint_as_float(((unsigned)s) << 16);
}

__device__ inline void gload16(const unsigned short* g, unsigned short* l) {
    __builtin_amdgcn_global_load_lds(
        (const __attribute__((address_space(1))) void*)g,
        (__attribute__((address_space(3))) void*)l, 16, 0, 0);
}

// ---------------------------------------------------------------- embed (f32)
__global__ __launch_bounds__(256)
void embed_kernel(float* __restrict__ x, const float* __restrict__ wte,
                  const float* __restrict__ wpe, const int* __restrict__ idx) {
    int row = blockIdx.x;
    int t = row & (Tt - 1);
    int id = idx[row];
    int c = threadIdx.x * 4;
    float4 a = *reinterpret_cast<const float4*>(&wte[(size_t)id * Dm + c]);
    float4 p = *reinterpret_cast<const float4*>(&wpe[(size_t)t * Dm + c]);
    float4 o;
    o.x = a.x + p.x; o.y = a.y + p.y; o.z = a.z + p.z; o.w = a.w + p.w;
    *reinterpret_cast<float4*>(&x[(size_t)row * Dm + c]) = o;
}

// ---------------------------------------------------------------- layernorm
__global__ __launch_bounds__(256)
void ln_kernel(unsigned short* __restrict__ y, const float* __restrict__ x,
               const float* __restrict__ w, const float* __restrict__ b) {
    int row = blockIdx.x;
    int tid = threadIdx.x;
    int lane = tid & 63, wv = tid >> 6;
    const float* xr = x + (size_t)row * Dm;
    float4 v = *reinterpret_cast<const float4*>(&xr[tid * 4]);
    float s1 = v.x + v.y + v.z + v.w;
    float s2 = v.x * v.x + v.y * v.y + v.z * v.z + v.w * v.w;
#pragma unroll
    for (int off = 1; off < 64; off <<= 1) {
        s1 += __shfl_xor(s1, off);
        s2 += __shfl_xor(s2, off);
    }
    __shared__ float r1[4], r2[4];
    if (lane == 0) { r1[wv] = s1; r2[wv] = s2; }
    __syncthreads();
    s1 = r1[0] + r1[1] + r1[2] + r1[3];
    s2 = r2[0] + r2[1] + r2[2] + r2[3];
    float mean = s1 * (1.0f / Dm);
    float var = s2 * (1.0f / Dm) - mean * mean;
    float rstd = rsqrtf(var + 1e-5f);
    float4 wvv = *reinterpret_cast<const float4*>(&w[tid * 4]);
    float4 bv = *reinterpret_cast<const float4*>(&b[tid * 4]);
    ushort4 o;
    o.x = f2bf((v.x - mean) * rstd * wvv.x + bv.x);
    o.y = f2bf((v.y - mean) * rstd * wvv.y + bv.y);
    o.z = f2bf((v.z - mean) * rstd * wvv.z + bv.z);
    o.w = f2bf((v.w - mean) * rstd * wvv.w + bv.w);
    *reinterpret_cast<ushort4*>(&y[(size_t)row * Dm + tid * 4]) = o;
}

// ------------------------------------------------- fused per-layer weight transpose
__global__ __launch_bounds__(256)
void transpose_layer(const float* __restrict__ qw, const float* __restrict__ ow,
                     const float* __restrict__ uw, const float* __restrict__ dw,
                     unsigned short* __restrict__ wTq, unsigned short* __restrict__ wTo,
                     unsigned short* __restrict__ wTu, unsigned short* __restrict__ wTd) {
    __shared__ float t[32][33];
    int tb = blockIdx.x;
    const float* src; unsigned short* dst; int K, N, nx, base;
    if (tb < 3072)      { src = qw; dst = wTq; K = 1024; N = 3072; nx = 96;  base = 0; }
    else if (tb < 4096) { src = ow; dst = wTo; K = 1024; N = 1024; nx = 32;  base = 3072; }
    else if (tb < 8192) { src = uw; dst = wTu; K = 1024; N = 4096; nx = 128; base = 4096; }
    else                { src = dw; dst = wTd; K = 4096; N = 1024; nx = 32;  base = 8192; }
    int tt = tb - base;
    int n0 = (tt % nx) * 32, k0 = (tt / nx) * 32;
    int tid = threadIdx.x;
    int r = tid >> 3, c4 = (tid & 7) * 4;
    float4 v = *reinterpret_cast<const float4*>(&src[(size_t)(k0 + r) * N + n0 + c4]);
    t[r][c4] = v.x; t[r][c4 + 1] = v.y; t[r][c4 + 2] = v.z; t[r][c4 + 3] = v.w;
    __syncthreads();
    int nr = tid >> 3, kc = (tid & 7) * 4;
    ushort4 o;
    o.x = f2bf(t[kc][nr]);
    o.y = f2bf(t[kc + 1][nr]);
    o.z = f2bf(t[kc + 2][nr]);
    o.w = f2bf(t[kc + 3][nr]);
    *reinterpret_cast<ushort4*>(&dst[(size_t)(n0 + nr) * K + k0 + kc]) = o;
}

// ------------------------------------------------- f32 rows -> bf16 rows
__global__ __launch_bounds__(128)
void cvt_rows(unsigned short* __restrict__ dst, const float* __restrict__ src) {
    int row = blockIdx.x;
    int t = threadIdx.x;
    const float* s = src + (size_t)row * Dm + t * 8;
    float4 f0 = *reinterpret_cast<const float4*>(s);
    float4 f1 = *reinterpret_cast<const float4*>(s + 4);
    ushort4 o0, o1;
    o0.x = f2bf(f0.x); o0.y = f2bf(f0.y); o0.z = f2bf(f0.z); o0.w = f2bf(f0.w);
    o1.x = f2bf(f1.x); o1.y = f2bf(f1.y); o1.z = f2bf(f1.z); o1.w = f2bf(f1.w);
    unsigned short* d = dst + (size_t)row * Dm + t * 8;
    *reinterpret_cast<ushort4*>(d) = o0;
    *reinterpret_cast<ushort4*>(d + 4) = o1;
}

// ================================================================ 256x256 pipelined GEMM
// 512 thr = 8 waves (2M x 4N). BK=32, 4-slot LDS ring, depth-3 prefetch,
// counted vmcnt (never 0 mid-loop), T2 XOR swizzle, raw s_barrier (no vmcnt drain).
// EPI 0: C bf16 = acc+bias. 1: C bf16 = gelu. 3: C f32 (guard col<Nv).
template<int EPI, int GN>
__global__ __launch_bounds__(512, 1)
void gemm256(const unsigned short* __restrict__ A, const unsigned short* __restrict__ B,
             const float* __restrict__ bias, void* __restrict__ Cp,
             int Nv, int K, int ldc, int ncol) {
    __shared__ unsigned short As[4][256 * 32];
    __shared__ unsigned short Bs[4][256 * 32];
    const int tid = threadIdx.x;
    const int lane = tid & 63, w = tid >> 6;
    const int wr = w >> 2, wc = w & 3;
    const int g = lane >> 4, lr = lane & 15;
    const int slotk = (lr >> 1) & 3;           // read-side swizzle key

    // XCD-aware bijective swizzle (m204)
    const int gx = gridDim.x;
    int flat = blockIdx.y * gx + blockIdx.x;
    int nwg = gx * gridDim.y;
    {
        int q = nwg >> 3, rr = nwg & 7;
        int xcd = flat & 7, pos = flat >> 3;
        flat = ((xcd < rr) ? (xcd * (q + 1)) : (rr * (q + 1) + (xcd - rr) * q)) + pos;
    }
    const int bm = (flat % gx) * 256;
    const int bn = (flat / gx) * 256;

    // staging geometry: wave w stages 16-row segments (w*2) and (w*2+1) of A and B.
    const int srow = lane >> 2;                       // row within segment
    const int gsrc = (lane & 3) ^ ((lane >> 3) & 3);  // pre-swizzled source granule
    const int rA0 = (w * 2 + 0) * 16 + srow;
    const int rA1 = (w * 2 + 1) * 16 + srow;
    const size_t aoff0 = (size_t)(bm + rA0) * K + gsrc * 8;
    const size_t aoff1 = (size_t)(bm + rA1) * K + gsrc * 8;
    int gb0 = bn + rA0, gb1 = bn + rA1;
    if (GN) { gb0 = (gb0 < Nv) ? gb0 : (Nv - 1); gb1 = (gb1 < Nv) ? gb1 : (Nv - 1); }
    const size_t boff0 = (size_t)gb0 * K + gsrc * 8;
    const size_t boff1 = (size_t)gb1 * K + gsrc * 8;
    unsigned short* lA0 = &As[0][(w * 2 + 0) * 512];
    unsigned short* lA1 = &As[0][(w * 2 + 1) * 512];
    unsigned short* lB0 = &Bs[0][(w * 2 + 0) * 512];
    unsigned short* lB1 = &Bs[0][(w * 2 + 1) * 512];

    const int nt = K >> 5;   // K-tiles (K multiple of 32, nt >= 3)

    f32x4 acc[8][4];
#pragma unroll
    for (int i = 0; i < 8; ++i)
#pragma unroll
        for (int j = 0; j < 4; ++j)
#pragma unroll
            for (int r = 0; r < 4; ++r) acc[i][j][r] = 0.f;

    // prologue: stage tiles 0,1,2 (4 loads each per wave)
#pragma unroll
    for (int tp = 0; tp < 3; ++tp) {
        const int kp = tp << 5;
        gload16(A + aoff0 + kp, lA0 + tp * 8192);
        gload16(B + boff0 + kp, lB0 + tp * 8192);
        gload16(A + aoff1 + kp, lA1 + tp * 8192);
        gload16(B + boff1 + kp, lB1 + tp * 8192);
    }
    asm volatile("s_waitcnt vmcnt(8)" ::: "memory");
    asm volatile("s_barrier" ::: "memory");

    for (int t = 0; t < nt; ++t) {
        const int bt = t & 3;
        const unsigned short* as = As[bt];
        const unsigned short* bs = Bs[bt];
        const int pf = t + 3;
        const int kp = pf << 5;
        const int so = (pf & 3) * 8192;

        // ---- phase 0: B frags + A frags (m-half 0) || prefetch pair 1
        bfrag bfr[4], af[4];
#pragma unroll
        for (int ni = 0; ni < 4; ++ni) {
            int row = wc * 64 + ni * 16 + lr;
            bfr[ni] = *reinterpret_cast<const bfrag*>(&bs[row * 32 + ((g ^ slotk) * 8)]);
        }
#pragma unroll
        for (int mi = 0; mi < 4; ++mi) {
            int row = wr * 128 + mi * 16 + lr;
            af[mi] = *reinterpret_cast<const bfrag*>(&as[row * 32 + ((g ^ slotk) * 8)]);
        }
        if (pf < nt) {
            gload16(A + aoff0 + kp, lA0 + so);
            gload16(B + boff0 + kp, lB0 + so);
        }
        asm volatile("s_barrier" ::: "memory");
        __builtin_amdgcn_s_setprio(1);
#pragma unroll
        for (int mi = 0; mi < 4; ++mi)
#pragma unroll
            for (int ni = 0; ni < 4; ++ni)
                acc[mi][ni] = __builtin_amdgcn_mfma_f32_16x16x32_bf16(
                    af[mi], bfr[ni], acc[mi][ni], 0, 0, 0);
        __builtin_amdgcn_s_setprio(0);
        asm volatile("s_barrier" ::: "memory");

        // ---- phase 1: A frags (m-half 1) || prefetch pair 2
#pragma unroll
        for (int mi = 0; mi < 4; ++mi) {
            int row = wr * 128 + (mi + 4) * 16 + lr;
            af[mi] = *reinterpret_cast<const bfrag*>(&as[row * 32 + ((g ^ slotk) * 8)]);
        }
        if (pf < nt) {
            gload16(A + aoff1 + kp, lA1 + so);
            gload16(B + boff1 + kp, lB1 + so);
        }
        asm volatile("s_barrier" ::: "memory");
        __builtin_amdgcn_s_setprio(1);
#pragma unroll
        for (int mi = 0; mi < 4; ++mi)
#pragma unroll
            for (int ni = 0; ni < 4; ++ni)
                acc[mi + 4][ni] = __builtin_amdgcn_mfma_f32_16x16x32_bf16(
                    af[mi], bfr[ni], acc[mi + 4][ni], 0, 0, 0);
        __builtin_amdgcn_s_setprio(0);
        // counted wait: ensure tile t+1 resident; keep t+2,t+3 in flight
        if (t + 3 < nt)      asm volatile("s_waitcnt vmcnt(8)" ::: "memory");
        else if (t + 2 < nt) asm volatile("s_waitcnt vmcnt(4)" ::: "memory");
        else if (t + 1 < nt) asm volatile("s_waitcnt vmcnt(0)" ::: "memory");
        asm volatile("s_barrier" ::: "memory");
    }

    unsigned short* Cb = (unsigned short*)Cp;
    float* Cf = (float*)Cp;
#pragma unroll
    for (int ni = 0; ni < 4; ++ni) {
        int col = bn + wc * 64 + ni * 16 + lr;
        if (GN && col >= Nv) continue;
        int gcol = ncol + col;
        float bi = bias[gcol];
#pragma unroll
        for (int mi = 0; mi < 8; ++mi) {
            int row0 = bm + wr * 128 + mi * 16 + g * 4;
#pragma unroll
            for (int r = 0; r < 4; ++r) {
                int row = row0 + r;
                float v = acc[mi][ni][r] + bi;
                if (EPI == 0) {
                    Cb[(size_t)row * ldc + gcol] = f2bf(v);
                } else if (EPI == 1) {
                    v = 0.5f * v * (1.0f + erff(v * 0.70710678118654752f));
                    Cb[(size_t)row * ldc + gcol] = f2bf(v);
                } else {
                    Cf[(size_t)row * ldc + gcol] = v;
                }
            }
        }
    }
}

// ---------------------------------------------------------------- 128x128 MFMA GEMM (proj/down)
template<int EPI, int GN>
__global__ __launch_bounds__(256)
void gemm_mfma(const unsigned short* __restrict__ A, const unsigned short* __restrict__ B,
               const float* __restrict__ bias, const float* __restrict__ R,
               void* __restrict__ Cp, int M, int Nv, int K, int ldc, int ncol) {
    __shared__ unsigned short As[128 * 64];
    __shared__ unsigned short Bs[128 * 64];
    const int tid = threadIdx.x;
    const int lane = tid & 63, wid = tid >> 6;
    const int gx = gridDim.x;
    int flat = blockIdx.y * gx + blockIdx.x;
    int nwg = gx * gridDim.y;
    {
        int q = nwg >> 3, rr = nwg & 7;
        int xcd = flat & 7, pos = flat >> 3;
        flat = ((xcd < rr) ? (xcd * (q + 1)) : (rr * (q + 1) + (xcd - rr) * q)) + pos;
    }
    const int bm = (flat % gx) * 128;
    const int bn = (flat / gx) * 128;
    const int wr = wid >> 1, wc = wid & 1;
    const int g = lane >> 4, lr = lane & 15;
    const int l8 = lane >> 3;
    const int k8 = (lane & 7) ^ l8;

    f32x4 acc[4][4];
#pragma unroll
    for (int i = 0; i < 4; ++i)
#pragma unroll
        for (int j = 0; j < 4; ++j)
#pragma unroll
            for (int r = 0; r < 4; ++r) acc[i][j][r] = 0.f;

    for (int k0 = 0; k0 < K; k0 += 64) {
#pragma unroll
        for (int jj = 0; jj < 8; ++jj) {
            int j = wid * 8 + jj;
            if (j < 16) {
                int row = j * 8 + l8;
                gload16(&A[(size_t)(bm + row) * K + k0 + k8 * 8], &As[j * 512]);
            } else {
                int j16 = j - 16;
                int row = j16 * 8 + l8;
                int grow = bn + row;
                if (GN) grow = (grow < Nv) ? grow : (Nv - 1);
                gload16(&B[(size_t)grow * K + k0 + k8 * 8], &Bs[j16 * 512]);
            }
        }
        __syncthreads();
#pragma unroll
        for (int ks = 0; ks < 2; ++ks) {
            bfrag af[4], bfr[4];
#pragma unroll
            for (int i = 0; i < 4; ++i) {
                int ra = wr * 64 + i * 16 + lr;
                af[i] = *reinterpret_cast<const bfrag*>(
                    &As[ra * 64 + ((((ks << 2) | g) ^ (ra & 7)) * 8)]);
                int rb = wc * 64 + i * 16 + lr;
                bfr[i] = *reinterpret_cast<const bfrag*>(
                    &Bs[rb * 64 + ((((ks << 2) | g) ^ (rb & 7)) * 8)]);
            }
#pragma unroll
            for (int mi = 0; mi < 4; ++mi)
#pragma unroll
                for (int ni = 0; ni < 4; ++ni)
                    acc[mi][ni] = __builtin_amdgcn_mfma_f32_16x16x32_bf16(
                        af[mi], bfr[ni], acc[mi][ni], 0, 0, 0);
        }
        __syncthreads();
    }

    unsigned short* Cb = (unsigned short*)Cp;
    float* Cf = (float*)Cp;
#pragma unroll
    for (int ni = 0; ni < 4; ++ni) {
        int col = bn + wc * 64 + ni * 16 + lr;
        if (GN && col >= Nv) continue;
        int gcol = ncol + col;
        float bi = bias[gcol];
#pragma unroll
        for (int mi = 0; mi < 4; ++mi) {
            int row0 = bm + wr * 64 + mi * 16 + g * 4;
#pragma unroll
            for (int r = 0; r < 4; ++r) {
                int row = row0 + r;
                float v = acc[mi][ni][r] + bi;
                if (EPI == 0) {
                    Cb[(size_t)row * ldc + gcol] = f2bf(v);
                } else if (EPI == 1) {
                    v = 0.5f * v * (1.0f + erff(v * 0.70710678118654752f));
                    Cb[(size_t)row * ldc + gcol] = f2bf(v);
                } else if (EPI == 2) {
                    Cf[(size_t)row * ldc + gcol] = R[(size_t)row * ldc + gcol] + v;
                } else {
                    Cf[(size_t)row * ldc + gcol] = v;
                }
            }
        }
    }
}

// ---------------------------------------------------------------- MFMA attention
__global__ __launch_bounds__(256)
void attn_mfma(const unsigned short* __restrict__ qkv, unsigned short* __restrict__ ob) {
    const int bq = blockIdx.x;
    const int h = blockIdx.y;
    const int b = blockIdx.z;
    const int tid = threadIdx.x, lane = tid & 63, w = tid >> 6;
    const int g = lane >> 4, lr = lane & 15;
    const int qg0 = bq * 128 + w * 32;

    __shared__ unsigned short Kt[64 * 72];
    __shared__ unsigned short Vt[64 * 72];
    __shared__ unsigned short Pl[4][32 * 72];
    unsigned short* Plw = Pl[w];

    bfrag aq[2][2];
#pragma unroll
    for (int qs = 0; qs < 2; ++qs)
#pragma unroll
        for (int ks = 0; ks < 2; ++ks) {
            int row = qg0 + qs * 16 + lr;
            aq[qs][ks] = *reinterpret_cast<const bfrag*>(
                &qkv[(size_t)(b * Tt + row) * 3072 + h * 64 + ks * 32 + g * 8]);
        }

    float mrow[2][4], lrow[2][4], osc[2][4];
    f32x4 oacc[2][4];
#pragma unroll
    for (int qs = 0; qs < 2; ++qs)
#pragma unroll
        for (int r = 0; r < 4; ++r) { mrow[qs][r] = -3.0e38f; lrow[qs][r] = 0.f; }
#pragma unroll
    for (int qs = 0; qs < 2; ++qs)
#pragma unroll
        for (int dn = 0; dn < 4; ++dn)
#pragma unroll
            for (int r = 0; r < 4; ++r) oacc[qs][dn][r] = 0.f;

    const int ntile = 2 * bq + 2;
    for (int kt = 0; kt < ntile; ++kt) {
        {
            int row = tid >> 2, seg = tid & 3;
            const unsigned short* sk =
                &qkv[(size_t)(b * Tt + kt * 64 + row) * 3072 + Dm + h * 64 + seg * 16];
            bfrag kv0 = *(const bfrag*)sk;
            bfrag kv1 = *(const bfrag*)(sk + 8);
            *reinterpret_cast<bfrag*>(&Kt[row * 72 + seg * 16]) = kv0;
            *reinterpret_cast<bfrag*>(&Kt[row * 72 + seg * 16 + 8]) = kv1;
            const uint4* sv = reinterpret_cast<const uint4*>(
                &qkv[(size_t)(b * Tt + kt * 64 + row) * 3072 + 2 * Dm + h * 64 + seg * 16]);
            uint4 u0 = sv[0], u1 = sv[1];
            uint4 a, r0, r1;
            a.x = (seg & 1) ? u0.y : u0.x; a.y = (seg & 1) ? u0.z : u0.y;
            a.z = (seg & 1) ? u0.w : u0.z; a.w = (seg & 1) ? u0.x : u0.w;
            r0.x = (seg & 2) ? a.z : a.x; r0.y = (seg & 2) ? a.w : a.y;
            r0.z = (seg & 2) ? a.x : a.z; r0.w = (seg & 2) ? a.y : a.w;
            a.x = (seg & 1) ? u1.y : u1.x; a.y = (seg & 1) ? u1.z : u1.y;
            a.z = (seg & 1) ? u1.w : u1.z; a.w = (seg & 1) ? u1.x : u1.w;
            r1.x = (seg & 2) ? a.z : a.x; r1.y = (seg & 2) ? a.w : a.y;
            r1.z = (seg & 2) ? a.x : a.z; r1.w = (seg & 2) ? a.y : a.w;
            unsigned w0[4] = {r0.x, r0.y, r0.z, r0.w};
            unsigned w1[4] = {r1.x, r1.y, r1.z, r1.w};
#pragma unroll
            for (int i = 0; i < 8; ++i) {
                int j = (i + 2 * seg) & 7;
                unsigned ww = w0[i >> 1];
                unsigned short val = (i & 1) ? (unsigned short)(ww >> 16)
                                             : (unsigned short)(ww & 0xffff);
                Vt[(seg * 16 + j) * 72 + row] = val;
            }
#pragma unroll
            for (int i = 0; i < 8; ++i) {
                int j = (i + 2 * seg) & 7;
                unsigned ww = w1[i >> 1];
                unsigned short val = (i & 1) ? (unsigned short)(ww >> 16)
                                             : (unsigned short)(ww & 0xffff);
                Vt[(seg * 16 + 8 + j) * 72 + row] = val;
            }
        }
        __syncthreads();

        bool active = (kt * 64 <= qg0 + 31);
        if (active) {
            f32x4 s[2][4];
#pragma unroll
            for (int qs = 0; qs < 2; ++qs)
#pragma unroll
                for (int n = 0; n < 4; ++n)
#pragma unroll
                    for (int r = 0; r < 4; ++r) s[qs][n][r] = 0.f;
            bfrag bk[4][2];
#pragma unroll
            for (int n = 0; n < 4; ++n)
#pragma unroll
                for (int ks = 0; ks < 2; ++ks)
                    bk[n][ks] = *reinterpret_cast<const bfrag*>(
                        &Kt[(n * 16 + lr) * 72 + ks * 32 + g * 8]);
#pragma unroll
            for (int qs = 0; qs < 2; ++qs)
#pragma unroll
                for (int n = 0; n < 4; ++n)
#pragma unroll
                    for (int ks = 0; ks < 2; ++ks)
                        s[qs][n] = __builtin_amdgcn_mfma_f32_16x16x32_bf16(
                            aq[qs][ks], bk[n][ks], s[qs][n], 0, 0, 0);

            bool mayMask = (kt * 64 + 63 > qg0);
            float pv[2][4][4];
#pragma unroll
            for (int qs = 0; qs < 2; ++qs) {
#pragma unroll
                for (int r = 0; r < 4; ++r) {
                    int qrow = qg0 + qs * 16 + g * 4 + r;
                    float v[4];
#pragma unroll
                    for (int n = 0; n < 4; ++n) {
                        float sv = s[qs][n][r] * 0.125f;
                        if (mayMask && (kt * 64 + n * 16 + lr > qrow)) sv = -3.0e38f;
                        v[n] = sv;
                    }
                    float tmax = fmaxf(fmaxf(v[0], v[1]), fmaxf(v[2], v[3]));
                    tmax = fmaxf(tmax, __shfl_xor(tmax, 1));
                    tmax = fmaxf(tmax, __shfl_xor(tmax, 2));
                    tmax = fmaxf(tmax, __shfl_xor(tmax, 4));
                    tmax = fmaxf(tmax, __shfl_xor(tmax, 8));
                    float mold = mrow[qs][r];
                    float mnew = fmaxf(mold, tmax);
                    float scl = expf(mold - mnew);
                    float psum = 0.f;
#pragma unroll
                    for (int n = 0; n < 4; ++n) {
                        float p = expf(v[n] - mnew);
                        pv[qs][n][r] = p;
                        psum += p;
                    }
                    psum += __shfl_xor(psum, 1);
                    psum += __shfl_xor(psum, 2);
                    psum += __shfl_xor(psum, 4);
                    psum += __shfl_xor(psum, 8);
                    lrow[qs][r] = lrow[qs][r] * scl + psum;
                    mrow[qs][r] = mnew;
                    osc[qs][r] = scl;
                }
            }
#pragma unroll
            for (int qs = 0; qs < 2; ++qs)
#pragma unroll
                for (int dn = 0; dn < 4; ++dn)
#pragma unroll
                    for (int r = 0; r < 4; ++r) oacc[qs][dn][r] *= osc[qs][r];
#pragma unroll
            for (int qs = 0; qs < 2; ++qs)
#pragma unroll
                for (int n = 0; n < 4; ++n)
#pragma unroll
                    for (int r = 0; r < 4; ++r)
                        Plw[(qs * 16 + g * 4 + r) * 72 + n * 16 + lr] = f2bf(pv[qs][n][r]);
            asm volatile("s_waitcnt lgkmcnt(0)" ::: "memory");
            bfrag ap[2][2], bv[4][2];
#pragma unroll
            for (int qs = 0; qs < 2; ++qs)
#pragma unroll
                for (int ks = 0; ks < 2; ++ks)
                    ap[qs][ks] = *reinterpret_cast<const bfrag*>(
                        &Plw[(qs * 16 + lr) * 72 + ks * 32 + g * 8]);
#pragma unroll
            for (int dn = 0; dn < 4; ++dn)
#pragma unroll
                for (int ks = 0; ks < 2; ++ks)
                    bv[dn][ks] = *reinterpret_cast<const bfrag*>(
                        &Vt[(dn * 16 + lr) * 72 + ks * 32 + g * 8]);
#pragma unroll
            for (int qs = 0; qs < 2; ++qs)
#pragma unroll
                for (int dn = 0; dn < 4; ++dn)
#pragma unroll
                    for (int ks = 0; ks < 2; ++ks)
                        oacc[qs][dn] = __builtin_amdgcn_mfma_f32_16x16x32_bf16(
                            ap[qs][ks], bv[dn][ks], oacc[qs][dn], 0, 0, 0);
        }
        __syncthreads();
    }

#pragma unroll
    for (int qs = 0; qs < 2; ++qs)
#pragma unroll
        for (int r = 0; r < 4; ++r) {
            float rinv = 1.0f / lrow[qs][r];
            int qrow = qg0 + qs * 16 + g * 4 + r;
#pragma unroll
            for (int dn = 0; dn < 4; ++dn)
                ob[(size_t)(b * Tt + qrow) * Dm + h * 64 + dn * 16 + lr] =
                    f2bf(oacc[qs][dn][r] * rinv);
        }
}

// ---------------------------------------------------------------- loss
__global__ __launch_bounds__(256)
void loss_row_kernel(float* __restrict__ nll, const float* __restrict__ logits,
                     const int* __restrict__ targets) {
    int row = blockIdx.x;
    int tid = threadIdx.x;
    const float* lr = logits + (size_t)row * Vv;
    __shared__ float red[256];
    float lmax = -INFINITY;
    for (int j = tid; j < Vv; j += 256) lmax = fmaxf(lmax, lr[j]);
    red[tid] = lmax;
    __syncthreads();
    for (int s = 128; s > 0; s >>= 1) {
        if (tid < s) red[tid] = fmaxf(red[tid], red[tid + s]);
        __syncthreads();
    }
    float m = red[0];
    __syncthreads();
    float lsum = 0.f;
    for (int j = tid; j < Vv; j += 256) lsum += expf(lr[j] - m);
    red[tid] = lsum;
    __syncthreads();
    for (int s = 128; s > 0; s >>= 1) {
        if (tid < s) red[tid] += red[tid + s];
        __syncthreads();
    }
    if (tid == 0) {
        float lse = m + logf(red[0]);
        nll[row] = lse - lr[targets[row]];
    }
}

__global__ __launch_bounds__(256)
void loss_reduce_kernel(float* __restrict__ loss, const float* __restrict__ nll) {
    int tid = threadIdx.x;
    __shared__ float red[256];
    float s = 0.f;
    for (int j = tid; j < Mrows; j += 256) s += nll[j];
    red[tid] = s;
    __syncthreads();
    for (int st = 128; st > 0; st >>= 1) {
        if (tid < st) red[tid] += red[tid + st];
        __syncthreads();
    }
    if (tid == 0) *loss = red[0] * (1.0f / Mrows);
}

// ---------------------------------------------------------------- launch
extern "C" void kernel_launch(void* const* d_in, const int* in_sizes, int n_in,
                              void* d_out, int out_size, void* d_ws, size_t ws_size,
                              hipStream_t stream) {
    const int* idx = (const int*)d_in[0];
    const int* targets = (const int*)d_in[1];
    const float* wte = (const float*)d_in[2];
    const float* wpe = (const float*)d_in[3];
    const float* ln1_w = (const float*)d_in[4];
    const float* ln1_b = (const float*)d_in[5];
    const float* qkv_w = (const float*)d_in[6];
    const float* qkv_b = (const float*)d_in[7];
    const float* o_w = (const float*)d_in[8];
    const float* o_b = (const float*)d_in[9];
    const float* ln2_w = (const float*)d_in[10];
    const float* ln2_b = (const float*)d_in[11];
    const float* up_w = (const float*)d_in[12];
    const float* up_b = (const float*)d_in[13];
    const float* down_w = (const float*)d_in[14];
    const float* down_b = (const float*)d_in[15];
    const float* lnf_w = (const float*)d_in[16];
    const float* lnf_b = (const float*)d_in[17];
    const float* lm_b = (const float*)d_in[18];

    float* logits = (float*)d_out;
    char* ws = (char*)d_ws;
    const size_t MB = 1 << 20;
    float* x            = (float*)(ws);                       // 16 MB
    unsigned short* y   = (unsigned short*)(ws + 16 * MB);    // 8 MB
    unsigned short* qkv = (unsigned short*)(ws + 24 * MB);    // 24 MB
    unsigned short* ob  = (unsigned short*)(ws + 48 * MB);    // 8 MB
    unsigned short* up  = (unsigned short*)(ws + 56 * MB);    // 32 MB
    unsigned short* wTq = (unsigned short*)(ws + 88 * MB);    // 6.3 MB
    unsigned short* wTo = (unsigned short*)(ws + 96 * MB);    // 2.1 MB
    unsigned short* wTu = (unsigned short*)(ws + 100 * MB);   // 8.4 MB
    unsigned short* wTd = (unsigned short*)(ws + 112 * MB);   // 8.4 MB
    float* nll          = (float*)(ws + 124 * MB);            // 16 KB
    unsigned short* wbf = (unsigned short*)(ws + 88 * MB);    // lm chunks (reuses wT*)

    embed_kernel<<<Mrows, 256, 0, stream>>>(x, wte, wpe, idx);

    for (int l = 0; l < Ll; ++l) {
        ln_kernel<<<Mrows, 256, 0, stream>>>(y, x, ln1_w + l * Dm, ln1_b + l * Dm);
        transpose_layer<<<12288, 256, 0, stream>>>(
            qkv_w + (size_t)l * Dm * 3 * Dm, o_w + (size_t)l * Dm * Dm,
            up_w + (size_t)l * Dm * 4 * Dm, down_w + (size_t)l * 4 * Dm * Dm,
            wTq, wTo, wTu, wTd);
        gemm256<0, 0><<<dim3(Mrows / 256, 3 * Dm / 256), 512, 0, stream>>>(
            y, wTq, qkv_b + (size_t)l * 3 * Dm, qkv, 3 * Dm, Dm, 3 * Dm, 0);
        attn_mfma<<<dim3(8, Hh, Bb), 256, 0, stream>>>(qkv, ob);
        gemm_mfma<2, 0><<<dim3(Mrows / 128, Dm / 128), 256, 0, stream>>>(
            ob, wTo, o_b + (size_t)l * Dm, x, x, Mrows, Dm, Dm, Dm, 0);
        ln_kernel<<<Mrows, 256, 0, stream>>>(y, x, ln2_w + l * Dm, ln2_b + l * Dm);
        gemm256<1, 0><<<dim3(Mrows / 256, 4 * Dm / 256), 512, 0, stream>>>(
            y, wTu, up_b + (size_t)l * 4 * Dm, up, 4 * Dm, Dm, 4 * Dm, 0);
        gemm_mfma<2, 0><<<dim3(Mrows / 128, Dm / 128), 256, 0, stream>>>(
            up, wTd, down_b + (size_t)l * Dm, x, x, Mrows, Dm, 4 * Dm, Dm, 0);
    }

    ln_kernel<<<Mrows, 256, 0, stream>>>(y, x, lnf_w, lnf_b);

    const int CH = 12800;
    for (int c0 = 0; c0 < Vv; c0 += CH) {
        int nv = (Vv - c0 < CH) ? (Vv - c0) : CH;
        cvt_rows<<<nv, 128, 0, stream>>>(wbf, wte + (size_t)c0 * Dm);
        gemm256<3, 1><<<dim3(Mrows / 256, (nv + 255) / 256), 512, 0, stream>>>(
            y, wbf, lm_b, logits, nv, Dm, Vv, c0);
    }

    loss_row_kernel<<<Mrows, 256, 0, stream>>>(nll, logits, targets);
    loss_reduce_kernel<<<1, 256, 0, stream>>>(logits + (size_t)Mrows * Vv, nll);
}

// Round 6
// 4880.670 us; speedup vs baseline: 9.3285x; 1.0700x over previous
//
#include <hip/hip_runtime.h>
#include <hip/hip_bf16.h>
#include <math.h>

typedef __attribute__((ext_vector_type(8))) short bfrag;   // 8 bf16 (4 VGPRs)
typedef __attribute__((ext_vector_type(4))) float f32x4;

static constexpr int Dm = 1024, Hh = 16, HD = 64, Ll = 12, Tt = 1024, Bb = 4;
static constexpr int Vv = 50257, Mrows = 4096;

__device__ inline unsigned short f2bf(float f) {  // RNE f32->bf16
    unsigned u = __float_as_uint(f);
    u += 0x7fffu + ((u >> 16) & 1u);
    return (unsigned short)(u >> 16);
}
__device__ inline float bf2f(unsigned short s) {
    return __uint_as_float(((unsigned)s) << 16);
}

__device__ inline void gload16(const unsigned short* g, unsigned short* l) {
    __builtin_amdgcn_global_load_lds(
        (const __attribute__((address_space(1))) void*)g,
        (__attribute__((address_space(3))) void*)l, 16, 0, 0);
}

// ---------------------------------------------------------------- embed (f32)
__global__ __launch_bounds__(256)
void embed_kernel(float* __restrict__ x, const float* __restrict__ wte,
                  const float* __restrict__ wpe, const int* __restrict__ idx) {
    int row = blockIdx.x;
    int t = row & (Tt - 1);
    int id = idx[row];
    int c = threadIdx.x * 4;
    float4 a = *reinterpret_cast<const float4*>(&wte[(size_t)id * Dm + c]);
    float4 p = *reinterpret_cast<const float4*>(&wpe[(size_t)t * Dm + c]);
    float4 o;
    o.x = a.x + p.x; o.y = a.y + p.y; o.z = a.z + p.z; o.w = a.w + p.w;
    *reinterpret_cast<float4*>(&x[(size_t)row * Dm + c]) = o;
}

// ---------------------------------------------------------------- layernorm
__global__ __launch_bounds__(256)
void ln_kernel(unsigned short* __restrict__ y, const float* __restrict__ x,
               const float* __restrict__ w, const float* __restrict__ b) {
    int row = blockIdx.x;
    int tid = threadIdx.x;
    int lane = tid & 63, wv = tid >> 6;
    const float* xr = x + (size_t)row * Dm;
    float4 v = *reinterpret_cast<const float4*>(&xr[tid * 4]);
    float s1 = v.x + v.y + v.z + v.w;
    float s2 = v.x * v.x + v.y * v.y + v.z * v.z + v.w * v.w;
#pragma unroll
    for (int off = 1; off < 64; off <<= 1) {
        s1 += __shfl_xor(s1, off);
        s2 += __shfl_xor(s2, off);
    }
    __shared__ float r1[4], r2[4];
    if (lane == 0) { r1[wv] = s1; r2[wv] = s2; }
    __syncthreads();
    s1 = r1[0] + r1[1] + r1[2] + r1[3];
    s2 = r2[0] + r2[1] + r2[2] + r2[3];
    float mean = s1 * (1.0f / Dm);
    float var = s2 * (1.0f / Dm) - mean * mean;
    float rstd = rsqrtf(var + 1e-5f);
    float4 wvv = *reinterpret_cast<const float4*>(&w[tid * 4]);
    float4 bv = *reinterpret_cast<const float4*>(&b[tid * 4]);
    ushort4 o;
    o.x = f2bf((v.x - mean) * rstd * wvv.x + bv.x);
    o.y = f2bf((v.y - mean) * rstd * wvv.y + bv.y);
    o.z = f2bf((v.z - mean) * rstd * wvv.z + bv.z);
    o.w = f2bf((v.w - mean) * rstd * wvv.w + bv.w);
    *reinterpret_cast<ushort4*>(&y[(size_t)row * Dm + tid * 4]) = o;
}

// ------------------------------------------------- fused per-layer weight transpose
__global__ __launch_bounds__(256)
void transpose_layer(const float* __restrict__ qw, const float* __restrict__ ow,
                     const float* __restrict__ uw, const float* __restrict__ dw,
                     unsigned short* __restrict__ wTq, unsigned short* __restrict__ wTo,
                     unsigned short* __restrict__ wTu, unsigned short* __restrict__ wTd) {
    __shared__ float t[32][33];
    int tb = blockIdx.x;
    const float* src; unsigned short* dst; int K, N, nx, base;
    if (tb < 3072)      { src = qw; dst = wTq; K = 1024; N = 3072; nx = 96;  base = 0; }
    else if (tb < 4096) { src = ow; dst = wTo; K = 1024; N = 1024; nx = 32;  base = 3072; }
    else if (tb < 8192) { src = uw; dst = wTu; K = 1024; N = 4096; nx = 128; base = 4096; }
    else                { src = dw; dst = wTd; K = 4096; N = 1024; nx = 32;  base = 8192; }
    int tt = tb - base;
    int n0 = (tt % nx) * 32, k0 = (tt / nx) * 32;
    int tid = threadIdx.x;
    int r = tid >> 3, c4 = (tid & 7) * 4;
    float4 v = *reinterpret_cast<const float4*>(&src[(size_t)(k0 + r) * N + n0 + c4]);
    t[r][c4] = v.x; t[r][c4 + 1] = v.y; t[r][c4 + 2] = v.z; t[r][c4 + 3] = v.w;
    __syncthreads();
    int nr = tid >> 3, kc = (tid & 7) * 4;
    ushort4 o;
    o.x = f2bf(t[kc][nr]);
    o.y = f2bf(t[kc + 1][nr]);
    o.z = f2bf(t[kc + 2][nr]);
    o.w = f2bf(t[kc + 3][nr]);
    *reinterpret_cast<ushort4*>(&dst[(size_t)(n0 + nr) * K + k0 + kc]) = o;
}

// ------------------------------------------------- f32 rows -> bf16 rows
__global__ __launch_bounds__(128)
void cvt_rows(unsigned short* __restrict__ dst, const float* __restrict__ src) {
    int row = blockIdx.x;
    int t = threadIdx.x;
    const float* s = src + (size_t)row * Dm + t * 8;
    float4 f0 = *reinterpret_cast<const float4*>(s);
    float4 f1 = *reinterpret_cast<const float4*>(s + 4);
    ushort4 o0, o1;
    o0.x = f2bf(f0.x); o0.y = f2bf(f0.y); o0.z = f2bf(f0.z); o0.w = f2bf(f0.w);
    o1.x = f2bf(f1.x); o1.y = f2bf(f1.y); o1.z = f2bf(f1.z); o1.w = f2bf(f1.w);
    unsigned short* d = dst + (size_t)row * Dm + t * 8;
    *reinterpret_cast<ushort4*>(d) = o0;
    *reinterpret_cast<ushort4*>(d + 4) = o1;
}

// ================================================================ 256x256 pipelined GEMM
// 512 thr = 8 waves (2M x 4N). BK=32, 4-slot LDS ring, depth-3 prefetch,
// counted vmcnt (never 0 mid-loop), T2 XOR swizzle, raw s_barrier.
// EPI 0: C bf16 = acc+bias. 1: C bf16 = gelu. 3: C f32 (guard col<Nv).
template<int EPI, int GN>
__global__ __launch_bounds__(512, 1)
void gemm256(const unsigned short* __restrict__ A, const unsigned short* __restrict__ B,
             const float* __restrict__ bias, void* __restrict__ Cp,
             int Nv, int K, int ldc, int ncol) {
    __shared__ unsigned short As[4][256 * 32];
    __shared__ unsigned short Bs[4][256 * 32];
    const int tid = threadIdx.x;
    const int lane = tid & 63, w = tid >> 6;
    const int wr = w >> 2, wc = w & 3;
    const int g = lane >> 4, lr = lane & 15;
    const int slotk = (lr >> 1) & 3;

    const int gx = gridDim.x;
    int flat = blockIdx.y * gx + blockIdx.x;
    int nwg = gx * gridDim.y;
    {
        int q = nwg >> 3, rr = nwg & 7;
        int xcd = flat & 7, pos = flat >> 3;
        flat = ((xcd < rr) ? (xcd * (q + 1)) : (rr * (q + 1) + (xcd - rr) * q)) + pos;
    }
    const int bm = (flat % gx) * 256;
    const int bn = (flat / gx) * 256;

    const int srow = lane >> 2;
    const int gsrc = (lane & 3) ^ ((lane >> 3) & 3);
    const int rA0 = (w * 2 + 0) * 16 + srow;
    const int rA1 = (w * 2 + 1) * 16 + srow;
    const size_t aoff0 = (size_t)(bm + rA0) * K + gsrc * 8;
    const size_t aoff1 = (size_t)(bm + rA1) * K + gsrc * 8;
    int gb0 = bn + rA0, gb1 = bn + rA1;
    if (GN) { gb0 = (gb0 < Nv) ? gb0 : (Nv - 1); gb1 = (gb1 < Nv) ? gb1 : (Nv - 1); }
    const size_t boff0 = (size_t)gb0 * K + gsrc * 8;
    const size_t boff1 = (size_t)gb1 * K + gsrc * 8;
    unsigned short* lA0 = &As[0][(w * 2 + 0) * 512];
    unsigned short* lA1 = &As[0][(w * 2 + 1) * 512];
    unsigned short* lB0 = &Bs[0][(w * 2 + 0) * 512];
    unsigned short* lB1 = &Bs[0][(w * 2 + 1) * 512];

    const int nt = K >> 5;

    f32x4 acc[8][4];
#pragma unroll
    for (int i = 0; i < 8; ++i)
#pragma unroll
        for (int j = 0; j < 4; ++j)
#pragma unroll
            for (int r = 0; r < 4; ++r) acc[i][j][r] = 0.f;

#pragma unroll
    for (int tp = 0; tp < 3; ++tp) {
        const int kp = tp << 5;
        gload16(A + aoff0 + kp, lA0 + tp * 8192);
        gload16(B + boff0 + kp, lB0 + tp * 8192);
        gload16(A + aoff1 + kp, lA1 + tp * 8192);
        gload16(B + boff1 + kp, lB1 + tp * 8192);
    }
    asm volatile("s_waitcnt vmcnt(8)" ::: "memory");
    asm volatile("s_barrier" ::: "memory");

    for (int t = 0; t < nt; ++t) {
        const int bt = t & 3;
        const unsigned short* as = As[bt];
        const unsigned short* bs = Bs[bt];
        const int pf = t + 3;
        const int kp = pf << 5;
        const int so = (pf & 3) * 8192;

        bfrag bfr[4], af[4];
#pragma unroll
        for (int ni = 0; ni < 4; ++ni) {
            int row = wc * 64 + ni * 16 + lr;
            bfr[ni] = *reinterpret_cast<const bfrag*>(&bs[row * 32 + ((g ^ slotk) * 8)]);
        }
#pragma unroll
        for (int mi = 0; mi < 4; ++mi) {
            int row = wr * 128 + mi * 16 + lr;
            af[mi] = *reinterpret_cast<const bfrag*>(&as[row * 32 + ((g ^ slotk) * 8)]);
        }
        if (pf < nt) {
            gload16(A + aoff0 + kp, lA0 + so);
            gload16(B + boff0 + kp, lB0 + so);
        }
        asm volatile("s_barrier" ::: "memory");
        __builtin_amdgcn_s_setprio(1);
#pragma unroll
        for (int mi = 0; mi < 4; ++mi)
#pragma unroll
            for (int ni = 0; ni < 4; ++ni)
                acc[mi][ni] = __builtin_amdgcn_mfma_f32_16x16x32_bf16(
                    af[mi], bfr[ni], acc[mi][ni], 0, 0, 0);
        __builtin_amdgcn_s_setprio(0);
        asm volatile("s_barrier" ::: "memory");

#pragma unroll
        for (int mi = 0; mi < 4; ++mi) {
            int row = wr * 128 + (mi + 4) * 16 + lr;
            af[mi] = *reinterpret_cast<const bfrag*>(&as[row * 32 + ((g ^ slotk) * 8)]);
        }
        if (pf < nt) {
            gload16(A + aoff1 + kp, lA1 + so);
            gload16(B + boff1 + kp, lB1 + so);
        }
        asm volatile("s_barrier" ::: "memory");
        __builtin_amdgcn_s_setprio(1);
#pragma unroll
        for (int mi = 0; mi < 4; ++mi)
#pragma unroll
            for (int ni = 0; ni < 4; ++ni)
                acc[mi + 4][ni] = __builtin_amdgcn_mfma_f32_16x16x32_bf16(
                    af[mi], bfr[ni], acc[mi + 4][ni], 0, 0, 0);
        __builtin_amdgcn_s_setprio(0);
        if (t + 3 < nt)      asm volatile("s_waitcnt vmcnt(8)" ::: "memory");
        else if (t + 2 < nt) asm volatile("s_waitcnt vmcnt(4)" ::: "memory");
        else if (t + 1 < nt) asm volatile("s_waitcnt vmcnt(0)" ::: "memory");
        asm volatile("s_barrier" ::: "memory");
    }

    unsigned short* Cb = (unsigned short*)Cp;
    float* Cf = (float*)Cp;
#pragma unroll
    for (int ni = 0; ni < 4; ++ni) {
        int col = bn + wc * 64 + ni * 16 + lr;
        if (GN && col >= Nv) continue;
        int gcol = ncol + col;
        float bi = bias[gcol];
#pragma unroll
        for (int mi = 0; mi < 8; ++mi) {
            int row0 = bm + wr * 128 + mi * 16 + g * 4;
#pragma unroll
            for (int r = 0; r < 4; ++r) {
                int row = row0 + r;
                float v = acc[mi][ni][r] + bi;
                if (EPI == 0) {
                    Cb[(size_t)row * ldc + gcol] = f2bf(v);
                } else if (EPI == 1) {
                    v = 0.5f * v * (1.0f + erff(v * 0.70710678118654752f));
                    Cb[(size_t)row * ldc + gcol] = f2bf(v);
                } else {
                    Cf[(size_t)row * ldc + gcol] = v;
                }
            }
        }
    }
}

// ---------------------------------------------------------------- 128x128 MFMA GEMM (proj/down)
template<int EPI, int GN>
__global__ __launch_bounds__(256)
void gemm_mfma(const unsigned short* __restrict__ A, const unsigned short* __restrict__ B,
               const float* __restrict__ bias, const float* __restrict__ R,
               void* __restrict__ Cp, int M, int Nv, int K, int ldc, int ncol) {
    __shared__ unsigned short As[128 * 64];
    __shared__ unsigned short Bs[128 * 64];
    const int tid = threadIdx.x;
    const int lane = tid & 63, wid = tid >> 6;
    const int gx = gridDim.x;
    int flat = blockIdx.y * gx + blockIdx.x;
    int nwg = gx * gridDim.y;
    {
        int q = nwg >> 3, rr = nwg & 7;
        int xcd = flat & 7, pos = flat >> 3;
        flat = ((xcd < rr) ? (xcd * (q + 1)) : (rr * (q + 1) + (xcd - rr) * q)) + pos;
    }
    const int bm = (flat % gx) * 128;
    const int bn = (flat / gx) * 128;
    const int wr = wid >> 1, wc = wid & 1;
    const int g = lane >> 4, lr = lane & 15;
    const int l8 = lane >> 3;
    const int k8 = (lane & 7) ^ l8;

    f32x4 acc[4][4];
#pragma unroll
    for (int i = 0; i < 4; ++i)
#pragma unroll
        for (int j = 0; j < 4; ++j)
#pragma unroll
            for (int r = 0; r < 4; ++r) acc[i][j][r] = 0.f;

    for (int k0 = 0; k0 < K; k0 += 64) {
#pragma unroll
        for (int jj = 0; jj < 8; ++jj) {
            int j = wid * 8 + jj;
            if (j < 16) {
                int row = j * 8 + l8;
                gload16(&A[(size_t)(bm + row) * K + k0 + k8 * 8], &As[j * 512]);
            } else {
                int j16 = j - 16;
                int row = j16 * 8 + l8;
                int grow = bn + row;
                if (GN) grow = (grow < Nv) ? grow : (Nv - 1);
                gload16(&B[(size_t)grow * K + k0 + k8 * 8], &Bs[j16 * 512]);
            }
        }
        __syncthreads();
#pragma unroll
        for (int ks = 0; ks < 2; ++ks) {
            bfrag af[4], bfr[4];
#pragma unroll
            for (int i = 0; i < 4; ++i) {
                int ra = wr * 64 + i * 16 + lr;
                af[i] = *reinterpret_cast<const bfrag*>(
                    &As[ra * 64 + ((((ks << 2) | g) ^ (ra & 7)) * 8)]);
                int rb = wc * 64 + i * 16 + lr;
                bfr[i] = *reinterpret_cast<const bfrag*>(
                    &Bs[rb * 64 + ((((ks << 2) | g) ^ (rb & 7)) * 8)]);
            }
#pragma unroll
            for (int mi = 0; mi < 4; ++mi)
#pragma unroll
                for (int ni = 0; ni < 4; ++ni)
                    acc[mi][ni] = __builtin_amdgcn_mfma_f32_16x16x32_bf16(
                        af[mi], bfr[ni], acc[mi][ni], 0, 0, 0);
        }
        __syncthreads();
    }

    unsigned short* Cb = (unsigned short*)Cp;
    float* Cf = (float*)Cp;
#pragma unroll
    for (int ni = 0; ni < 4; ++ni) {
        int col = bn + wc * 64 + ni * 16 + lr;
        if (GN && col >= Nv) continue;
        int gcol = ncol + col;
        float bi = bias[gcol];
#pragma unroll
        for (int mi = 0; mi < 4; ++mi) {
            int row0 = bm + wr * 64 + mi * 16 + g * 4;
#pragma unroll
            for (int r = 0; r < 4; ++r) {
                int row = row0 + r;
                float v = acc[mi][ni][r] + bi;
                if (EPI == 0) {
                    Cb[(size_t)row * ldc + gcol] = f2bf(v);
                } else if (EPI == 1) {
                    v = 0.5f * v * (1.0f + erff(v * 0.70710678118654752f));
                    Cb[(size_t)row * ldc + gcol] = f2bf(v);
                } else if (EPI == 2) {
                    Cf[(size_t)row * ldc + gcol] = R[(size_t)row * ldc + gcol] + v;
                } else {
                    Cf[(size_t)row * ldc + gcol] = v;
                }
            }
        }
    }
}

// ---------------------------------------------------------------- MFMA attention
__global__ __launch_bounds__(256)
void attn_mfma(const unsigned short* __restrict__ qkv, unsigned short* __restrict__ ob) {
    const int bq = blockIdx.x;
    const int h = blockIdx.y;
    const int b = blockIdx.z;
    const int tid = threadIdx.x, lane = tid & 63, w = tid >> 6;
    const int g = lane >> 4, lr = lane & 15;
    const int qg0 = bq * 128 + w * 32;

    __shared__ unsigned short Kt[64 * 72];
    __shared__ unsigned short Vt[64 * 72];
    __shared__ unsigned short Pl[4][32 * 72];
    unsigned short* Plw = Pl[w];

    bfrag aq[2][2];
#pragma unroll
    for (int qs = 0; qs < 2; ++qs)
#pragma unroll
        for (int ks = 0; ks < 2; ++ks) {
            int row = qg0 + qs * 16 + lr;
            aq[qs][ks] = *reinterpret_cast<const bfrag*>(
                &qkv[(size_t)(b * Tt + row) * 3072 + h * 64 + ks * 32 + g * 8]);
        }

    float mrow[2][4], lrow[2][4], osc[2][4];
    f32x4 oacc[2][4];
#pragma unroll
    for (int qs = 0; qs < 2; ++qs)
#pragma unroll
        for (int r = 0; r < 4; ++r) { mrow[qs][r] = -3.0e38f; lrow[qs][r] = 0.f; }
#pragma unroll
    for (int qs = 0; qs < 2; ++qs)
#pragma unroll
        for (int dn = 0; dn < 4; ++dn)
#pragma unroll
            for (int r = 0; r < 4; ++r) oacc[qs][dn][r] = 0.f;

    const int ntile = 2 * bq + 2;
    for (int kt = 0; kt < ntile; ++kt) {
        {
            int row = tid >> 2, seg = tid & 3;
            const unsigned short* sk =
                &qkv[(size_t)(b * Tt + kt * 64 + row) * 3072 + Dm + h * 64 + seg * 16];
            bfrag kv0 = *(const bfrag*)sk;
            bfrag kv1 = *(const bfrag*)(sk + 8);
            *reinterpret_cast<bfrag*>(&Kt[row * 72 + seg * 16]) = kv0;
            *reinterpret_cast<bfrag*>(&Kt[row * 72 + seg * 16 + 8]) = kv1;
            const uint4* sv = reinterpret_cast<const uint4*>(
                &qkv[(size_t)(b * Tt + kt * 64 + row) * 3072 + 2 * Dm + h * 64 + seg * 16]);
            uint4 u0 = sv[0], u1 = sv[1];
            uint4 a, r0, r1;
            a.x = (seg & 1) ? u0.y : u0.x; a.y = (seg & 1) ? u0.z : u0.y;
            a.z = (seg & 1) ? u0.w : u0.z; a.w = (seg & 1) ? u0.x : u0.w;
            r0.x = (seg & 2) ? a.z : a.x; r0.y = (seg & 2) ? a.w : a.y;
            r0.z = (seg & 2) ? a.x : a.z; r0.w = (seg & 2) ? a.y : a.w;
            a.x = (seg & 1) ? u1.y : u1.x; a.y = (seg & 1) ? u1.z : u1.y;
            a.z = (seg & 1) ? u1.w : u1.z; a.w = (seg & 1) ? u1.x : u1.w;
            r1.x = (seg & 2) ? a.z : a.x; r1.y = (seg & 2) ? a.w : a.y;
            r1.z = (seg & 2) ? a.x : a.z; r1.w = (seg & 2) ? a.y : a.w;
            unsigned w0[4] = {r0.x, r0.y, r0.z, r0.w};
            unsigned w1[4] = {r1.x, r1.y, r1.z, r1.w};
#pragma unroll
            for (int i = 0; i < 8; ++i) {
                int j = (i + 2 * seg) & 7;
                unsigned ww = w0[i >> 1];
                unsigned short val = (i & 1) ? (unsigned short)(ww >> 16)
                                             : (unsigned short)(ww & 0xffff);
                Vt[(seg * 16 + j) * 72 + row] = val;
            }
#pragma unroll
            for (int i = 0; i < 8; ++i) {
                int j = (i + 2 * seg) & 7;
                unsigned ww = w1[i >> 1];
                unsigned short val = (i & 1) ? (unsigned short)(ww >> 16)
                                             : (unsigned short)(ww & 0xffff);
                Vt[(seg * 16 + 8 + j) * 72 + row] = val;
            }
        }
        __syncthreads();

        bool active = (kt * 64 <= qg0 + 31);
        if (active) {
            f32x4 s[2][4];
#pragma unroll
            for (int qs = 0; qs < 2; ++qs)
#pragma unroll
                for (int n = 0; n < 4; ++n)
#pragma unroll
                    for (int r = 0; r < 4; ++r) s[qs][n][r] = 0.f;
            bfrag bk[4][2];
#pragma unroll
            for (int n = 0; n < 4; ++n)
#pragma unroll
                for (int ks = 0; ks < 2; ++ks)
                    bk[n][ks] = *reinterpret_cast<const bfrag*>(
                        &Kt[(n * 16 + lr) * 72 + ks * 32 + g * 8]);
#pragma unroll
            for (int qs = 0; qs < 2; ++qs)
#pragma unroll
                for (int n = 0; n < 4; ++n)
#pragma unroll
                    for (int ks = 0; ks < 2; ++ks)
                        s[qs][n] = __builtin_amdgcn_mfma_f32_16x16x32_bf16(
                            aq[qs][ks], bk[n][ks], s[qs][n], 0, 0, 0);

            bool mayMask = (kt * 64 + 63 > qg0);
            float pv[2][4][4];
#pragma unroll
            for (int qs = 0; qs < 2; ++qs) {
#pragma unroll
                for (int r = 0; r < 4; ++r) {
                    int qrow = qg0 + qs * 16 + g * 4 + r;
                    float v[4];
#pragma unroll
                    for (int n = 0; n < 4; ++n) {
                        float sv = s[qs][n][r] * 0.125f;
                        if (mayMask && (kt * 64 + n * 16 + lr > qrow)) sv = -3.0e38f;
                        v[n] = sv;
                    }
                    float tmax = fmaxf(fmaxf(v[0], v[1]), fmaxf(v[2], v[3]));
                    tmax = fmaxf(tmax, __shfl_xor(tmax, 1));
                    tmax = fmaxf(tmax, __shfl_xor(tmax, 2));
                    tmax = fmaxf(tmax, __shfl_xor(tmax, 4));
                    tmax = fmaxf(tmax, __shfl_xor(tmax, 8));
                    float mold = mrow[qs][r];
                    float mnew = fmaxf(mold, tmax);
                    float scl = expf(mold - mnew);
                    float psum = 0.f;
#pragma unroll
                    for (int n = 0; n < 4; ++n) {
                        float p = expf(v[n] - mnew);
                        pv[qs][n][r] = p;
                        psum += p;
                    }
                    psum += __shfl_xor(psum, 1);
                    psum += __shfl_xor(psum, 2);
                    psum += __shfl_xor(psum, 4);
                    psum += __shfl_xor(psum, 8);
                    lrow[qs][r] = lrow[qs][r] * scl + psum;
                    mrow[qs][r] = mnew;
                    osc[qs][r] = scl;
                }
            }
#pragma unroll
            for (int qs = 0; qs < 2; ++qs)
#pragma unroll
                for (int dn = 0; dn < 4; ++dn)
#pragma unroll
                    for (int r = 0; r < 4; ++r) oacc[qs][dn][r] *= osc[qs][r];
#pragma unroll
            for (int qs = 0; qs < 2; ++qs)
#pragma unroll
                for (int n = 0; n < 4; ++n)
#pragma unroll
                    for (int r = 0; r < 4; ++r)
                        Plw[(qs * 16 + g * 4 + r) * 72 + n * 16 + lr] = f2bf(pv[qs][n][r]);
            asm volatile("s_waitcnt lgkmcnt(0)" ::: "memory");
            bfrag ap[2][2], bv[4][2];
#pragma unroll
            for (int qs = 0; qs < 2; ++qs)
#pragma unroll
                for (int ks = 0; ks < 2; ++ks)
                    ap[qs][ks] = *reinterpret_cast<const bfrag*>(
                        &Plw[(qs * 16 + lr) * 72 + ks * 32 + g * 8]);
#pragma unroll
            for (int dn = 0; dn < 4; ++dn)
#pragma unroll
                for (int ks = 0; ks < 2; ++ks)
                    bv[dn][ks] = *reinterpret_cast<const bfrag*>(
                        &Vt[(dn * 16 + lr) * 72 + ks * 32 + g * 8]);
#pragma unroll
            for (int qs = 0; qs < 2; ++qs)
#pragma unroll
                for (int dn = 0; dn < 4; ++dn)
#pragma unroll
                    for (int ks = 0; ks < 2; ++ks)
                        oacc[qs][dn] = __builtin_amdgcn_mfma_f32_16x16x32_bf16(
                            ap[qs][ks], bv[dn][ks], oacc[qs][dn], 0, 0, 0);
        }
        __syncthreads();
    }

#pragma unroll
    for (int qs = 0; qs < 2; ++qs)
#pragma unroll
        for (int r = 0; r < 4; ++r) {
            float rinv = 1.0f / lrow[qs][r];
            int qrow = qg0 + qs * 16 + g * 4 + r;
#pragma unroll
            for (int dn = 0; dn < 4; ++dn)
                ob[(size_t)(b * Tt + qrow) * Dm + h * 64 + dn * 16 + lr] =
                    f2bf(oacc[qs][dn][r] * rinv);
        }
}

// ---------------------------------------------------------------- loss (single-pass online LSE)
__global__ __launch_bounds__(512)
void loss_row_kernel(float* __restrict__ nll, const float* __restrict__ logits,
                     const int* __restrict__ targets) {
    const int row = blockIdx.x;
    const int tid = threadIdx.x;
    const int lane = tid & 63, wv = tid >> 6;
    const float* lr = logits + (size_t)row * Vv;

    // row base offset mod 4 floats == row & 3 -> lead-in to 16B alignment
    const int lead = (4 - (row & 3)) & 3;
    const int nvec = (Vv - lead) >> 2;          // full float4s
    const int tail = Vv - lead - (nvec << 2);

    float m = -3.0e38f, s = 0.f;
    if (tid < lead) {
        float v = lr[tid];
        m = v; s = 1.f;
    }
    for (int k = tid; k < nvec; k += 512) {
        float4 v = *reinterpret_cast<const float4*>(lr + lead + (k << 2));
        float tm = fmaxf(fmaxf(v.x, v.y), fmaxf(v.z, v.w));
        float nm = fmaxf(m, tm);
        s = s * __expf(m - nm)
          + __expf(v.x - nm) + __expf(v.y - nm) + __expf(v.z - nm) + __expf(v.w - nm);
        m = nm;
    }
    if (tid < tail) {
        float v = lr[lead + (nvec << 2) + tid];
        float nm = fmaxf(m, v);
        s = s * __expf(m - nm) + __expf(v - nm);
        m = nm;
    }
    // wave combine of (m, s)
#pragma unroll
    for (int off = 1; off < 64; off <<= 1) {
        float om = __shfl_xor(m, off);
        float os = __shfl_xor(s, off);
        float nm = fmaxf(m, om);
        s = s * __expf(m - nm) + os * __expf(om - nm);
        m = nm;
    }
    __shared__ float rm[8], rs[8];
    if (lane == 0) { rm[wv] = m; rs[wv] = s; }
    __syncthreads();
    if (tid == 0) {
        float M = rm[0];
#pragma unroll
        for (int i = 1; i < 8; ++i) M = fmaxf(M, rm[i]);
        float S = 0.f;
#pragma unroll
        for (int i = 0; i < 8; ++i) S += rs[i] * __expf(rm[i] - M);
        float lse = M + __logf(S);
        nll[row] = lse - lr[targets[row]];
    }
}

__global__ __launch_bounds__(256)
void loss_reduce_kernel(float* __restrict__ loss, const float* __restrict__ nll) {
    int tid = threadIdx.x;
    __shared__ float red[256];
    float s = 0.f;
    for (int j = tid; j < Mrows; j += 256) s += nll[j];
    red[tid] = s;
    __syncthreads();
    for (int st = 128; st > 0; st >>= 1) {
        if (tid < st) red[tid] += red[tid + st];
        __syncthreads();
    }
    if (tid == 0) *loss = red[0] * (1.0f / Mrows);
}

// ---------------------------------------------------------------- launch
extern "C" void kernel_launch(void* const* d_in, const int* in_sizes, int n_in,
                              void* d_out, int out_size, void* d_ws, size_t ws_size,
                              hipStream_t stream) {
    const int* idx = (const int*)d_in[0];
    const int* targets = (const int*)d_in[1];
    const float* wte = (const float*)d_in[2];
    const float* wpe = (const float*)d_in[3];
    const float* ln1_w = (const float*)d_in[4];
    const float* ln1_b = (const float*)d_in[5];
    const float* qkv_w = (const float*)d_in[6];
    const float* qkv_b = (const float*)d_in[7];
    const float* o_w = (const float*)d_in[8];
    const float* o_b = (const float*)d_in[9];
    const float* ln2_w = (const float*)d_in[10];
    const float* ln2_b = (const float*)d_in[11];
    const float* up_w = (const float*)d_in[12];
    const float* up_b = (const float*)d_in[13];
    const float* down_w = (const float*)d_in[14];
    const float* down_b = (const float*)d_in[15];
    const float* lnf_w = (const float*)d_in[16];
    const float* lnf_b = (const float*)d_in[17];
    const float* lm_b = (const float*)d_in[18];

    float* logits = (float*)d_out;
    char* ws = (char*)d_ws;
    const size_t MB = 1 << 20;
    float* x            = (float*)(ws);                       // 16 MB
    unsigned short* y   = (unsigned short*)(ws + 16 * MB);    // 8 MB
    unsigned short* qkv = (unsigned short*)(ws + 24 * MB);    // 24 MB
    unsigned short* ob  = (unsigned short*)(ws + 48 * MB);    // 8 MB
    unsigned short* up  = (unsigned short*)(ws + 56 * MB);    // 32 MB
    unsigned short* wTq = (unsigned short*)(ws + 88 * MB);    // 6.3 MB
    unsigned short* wTo = (unsigned short*)(ws + 96 * MB);    // 2.1 MB
    unsigned short* wTu = (unsigned short*)(ws + 100 * MB);   // 8.4 MB
    unsigned short* wTd = (unsigned short*)(ws + 112 * MB);   // 8.4 MB
    float* nll          = (float*)(ws + 127 * MB);            // 16 KB
    // lm phase: whole-wte bf16 at ws+24 MB (qkv/ob/up/wT* dead by then), 103 MB
    unsigned short* wbf = (unsigned short*)(ws + 24 * MB);

    embed_kernel<<<Mrows, 256, 0, stream>>>(x, wte, wpe, idx);

    for (int l = 0; l < Ll; ++l) {
        ln_kernel<<<Mrows, 256, 0, stream>>>(y, x, ln1_w + l * Dm, ln1_b + l * Dm);
        transpose_layer<<<12288, 256, 0, stream>>>(
            qkv_w + (size_t)l * Dm * 3 * Dm, o_w + (size_t)l * Dm * Dm,
            up_w + (size_t)l * Dm * 4 * Dm, down_w + (size_t)l * 4 * Dm * Dm,
            wTq, wTo, wTu, wTd);
        gemm256<0, 0><<<dim3(Mrows / 256, 3 * Dm / 256), 512, 0, stream>>>(
            y, wTq, qkv_b + (size_t)l * 3 * Dm, qkv, 3 * Dm, Dm, 3 * Dm, 0);
        attn_mfma<<<dim3(8, Hh, Bb), 256, 0, stream>>>(qkv, ob);
        gemm_mfma<2, 0><<<dim3(Mrows / 128, Dm / 128), 256, 0, stream>>>(
            ob, wTo, o_b + (size_t)l * Dm, x, x, Mrows, Dm, Dm, Dm, 0);
        ln_kernel<<<Mrows, 256, 0, stream>>>(y, x, ln2_w + l * Dm, ln2_b + l * Dm);
        gemm256<1, 0><<<dim3(Mrows / 256, 4 * Dm / 256), 512, 0, stream>>>(
            y, wTu, up_b + (size_t)l * 4 * Dm, up, 4 * Dm, Dm, 4 * Dm, 0);
        gemm_mfma<2, 0><<<dim3(Mrows / 128, Dm / 128), 256, 0, stream>>>(
            up, wTd, down_b + (size_t)l * Dm, x, x, Mrows, Dm, 4 * Dm, Dm, 0);
    }

    ln_kernel<<<Mrows, 256, 0, stream>>>(y, x, lnf_w, lnf_b);

    // lm_head: convert whole wte once, then one GEMM
    cvt_rows<<<Vv, 128, 0, stream>>>(wbf, wte);
    gemm256<3, 1><<<dim3(Mrows / 256, (Vv + 255) / 256), 512, 0, stream>>>(
        y, wbf, lm_b, logits, Vv, Dm, Vv, 0);

    loss_row_kernel<<<Mrows, 512, 0, stream>>>(nll, logits, targets);
    loss_reduce_kernel<<<1, 256, 0, stream>>>(logits + (size_t)Mrows * Vv, nll);
}

// Round 7
// 4622.051 us; speedup vs baseline: 9.8505x; 1.0560x over previous
//
#include <hip/hip_runtime.h>
#include <hip/hip_bf16.h>
#include <math.h>

typedef __attribute__((ext_vector_type(8))) short bfrag;   // 8 bf16 (4 VGPRs)
typedef __attribute__((ext_vector_type(4))) float f32x4;

static constexpr int Dm = 1024, Hh = 16, HD = 64, Ll = 12, Tt = 1024, Bb = 4;
static constexpr int Vv = 50257, Mrows = 4096;

__device__ inline unsigned short f2bf(float f) {  // RNE f32->bf16
    unsigned u = __float_as_uint(f);
    u += 0x7fffu + ((u >> 16) & 1u);
    return (unsigned short)(u >> 16);
}
__device__ inline float bf2f(unsigned short s) {
    return __uint_as_float(((unsigned)s) << 16);
}

__device__ inline void gload16(const unsigned short* g, unsigned short* l) {
    __builtin_amdgcn_global_load_lds(
        (const __attribute__((address_space(1))) void*)g,
        (__attribute__((address_space(3))) void*)l, 16, 0, 0);
}

// ---------------------------------------------------------------- embed (f32)
__global__ __launch_bounds__(256)
void embed_kernel(float* __restrict__ x, const float* __restrict__ wte,
                  const float* __restrict__ wpe, const int* __restrict__ idx) {
    int row = blockIdx.x;
    int t = row & (Tt - 1);
    int id = idx[row];
    int c = threadIdx.x * 4;
    float4 a = *reinterpret_cast<const float4*>(&wte[(size_t)id * Dm + c]);
    float4 p = *reinterpret_cast<const float4*>(&wpe[(size_t)t * Dm + c]);
    float4 o;
    o.x = a.x + p.x; o.y = a.y + p.y; o.z = a.z + p.z; o.w = a.w + p.w;
    *reinterpret_cast<float4*>(&x[(size_t)row * Dm + c]) = o;
}

// ---------------------------------------------------------------- layernorm
__global__ __launch_bounds__(256)
void ln_kernel(unsigned short* __restrict__ y, const float* __restrict__ x,
               const float* __restrict__ w, const float* __restrict__ b) {
    int row = blockIdx.x;
    int tid = threadIdx.x;
    int lane = tid & 63, wv = tid >> 6;
    const float* xr = x + (size_t)row * Dm;
    float4 v = *reinterpret_cast<const float4*>(&xr[tid * 4]);
    float s1 = v.x + v.y + v.z + v.w;
    float s2 = v.x * v.x + v.y * v.y + v.z * v.z + v.w * v.w;
#pragma unroll
    for (int off = 1; off < 64; off <<= 1) {
        s1 += __shfl_xor(s1, off);
        s2 += __shfl_xor(s2, off);
    }
    __shared__ float r1[4], r2[4];
    if (lane == 0) { r1[wv] = s1; r2[wv] = s2; }
    __syncthreads();
    s1 = r1[0] + r1[1] + r1[2] + r1[3];
    s2 = r2[0] + r2[1] + r2[2] + r2[3];
    float mean = s1 * (1.0f / Dm);
    float var = s2 * (1.0f / Dm) - mean * mean;
    float rstd = rsqrtf(var + 1e-5f);
    float4 wvv = *reinterpret_cast<const float4*>(&w[tid * 4]);
    float4 bv = *reinterpret_cast<const float4*>(&b[tid * 4]);
    ushort4 o;
    o.x = f2bf((v.x - mean) * rstd * wvv.x + bv.x);
    o.y = f2bf((v.y - mean) * rstd * wvv.y + bv.y);
    o.z = f2bf((v.z - mean) * rstd * wvv.z + bv.z);
    o.w = f2bf((v.w - mean) * rstd * wvv.w + bv.w);
    *reinterpret_cast<ushort4*>(&y[(size_t)row * Dm + tid * 4]) = o;
}

// ------------------------------------------------- fused per-layer weight transpose
__global__ __launch_bounds__(256)
void transpose_layer(const float* __restrict__ qw, const float* __restrict__ ow,
                     const float* __restrict__ uw, const float* __restrict__ dw,
                     unsigned short* __restrict__ wTq, unsigned short* __restrict__ wTo,
                     unsigned short* __restrict__ wTu, unsigned short* __restrict__ wTd) {
    __shared__ float t[32][33];
    int tb = blockIdx.x;
    const float* src; unsigned short* dst; int K, N, nx, base;
    if (tb < 3072)      { src = qw; dst = wTq; K = 1024; N = 3072; nx = 96;  base = 0; }
    else if (tb < 4096) { src = ow; dst = wTo; K = 1024; N = 1024; nx = 32;  base = 3072; }
    else if (tb < 8192) { src = uw; dst = wTu; K = 1024; N = 4096; nx = 128; base = 4096; }
    else                { src = dw; dst = wTd; K = 4096; N = 1024; nx = 32;  base = 8192; }
    int tt = tb - base;
    int n0 = (tt % nx) * 32, k0 = (tt / nx) * 32;
    int tid = threadIdx.x;
    int r = tid >> 3, c4 = (tid & 7) * 4;
    float4 v = *reinterpret_cast<const float4*>(&src[(size_t)(k0 + r) * N + n0 + c4]);
    t[r][c4] = v.x; t[r][c4 + 1] = v.y; t[r][c4 + 2] = v.z; t[r][c4 + 3] = v.w;
    __syncthreads();
    int nr = tid >> 3, kc = (tid & 7) * 4;
    ushort4 o;
    o.x = f2bf(t[kc][nr]);
    o.y = f2bf(t[kc + 1][nr]);
    o.z = f2bf(t[kc + 2][nr]);
    o.w = f2bf(t[kc + 3][nr]);
    *reinterpret_cast<ushort4*>(&dst[(size_t)(n0 + nr) * K + k0 + kc]) = o;
}

// ------------------------------------------------- f32 rows -> bf16 rows
__global__ __launch_bounds__(128)
void cvt_rows(unsigned short* __restrict__ dst, const float* __restrict__ src) {
    int row = blockIdx.x;
    int t = threadIdx.x;
    const float* s = src + (size_t)row * Dm + t * 8;
    float4 f0 = *reinterpret_cast<const float4*>(s);
    float4 f1 = *reinterpret_cast<const float4*>(s + 4);
    ushort4 o0, o1;
    o0.x = f2bf(f0.x); o0.y = f2bf(f0.y); o0.z = f2bf(f0.z); o0.w = f2bf(f0.w);
    o1.x = f2bf(f1.x); o1.y = f2bf(f1.y); o1.z = f2bf(f1.z); o1.w = f2bf(f1.w);
    unsigned short* d = dst + (size_t)row * Dm + t * 8;
    *reinterpret_cast<ushort4*>(d) = o0;
    *reinterpret_cast<ushort4*>(d + 4) = o1;
}

// ================================================================ 256x256 pipelined GEMM
// 512 thr = 8 waves (2M x 4N). BK=32, 4-slot LDS ring, depth-3 prefetch,
// merged phase: {12 ds_read || 4 gload -> 32 MFMA -> counted vmcnt -> 1 barrier}.
// EPI 0: C bf16 = acc+bias. 1: C bf16 = gelu. 3: C f32 (guard col<Nv).
template<int EPI, int GN>
__global__ __launch_bounds__(512, 2)
void gemm256(const unsigned short* __restrict__ A, const unsigned short* __restrict__ B,
             const float* __restrict__ bias, void* __restrict__ Cp,
             int Nv, int K, int ldc, int ncol) {
    __shared__ unsigned short As[4][256 * 32];
    __shared__ unsigned short Bs[4][256 * 32];
    const int tid = threadIdx.x;
    const int lane = tid & 63, w = tid >> 6;
    const int wr = w >> 2, wc = w & 3;
    const int g = lane >> 4, lr = lane & 15;
    const int slotk = (lr >> 1) & 3;

    const int gx = gridDim.x;
    int flat = blockIdx.y * gx + blockIdx.x;
    int nwg = gx * gridDim.y;
    {
        int q = nwg >> 3, rr = nwg & 7;
        int xcd = flat & 7, pos = flat >> 3;
        flat = ((xcd < rr) ? (xcd * (q + 1)) : (rr * (q + 1) + (xcd - rr) * q)) + pos;
    }
    const int bm = (flat % gx) * 256;
    const int bn = (flat / gx) * 256;

    const int srow = lane >> 2;
    const int gsrc = (lane & 3) ^ ((lane >> 3) & 3);
    const int rA0 = (w * 2 + 0) * 16 + srow;
    const int rA1 = (w * 2 + 1) * 16 + srow;
    const size_t aoff0 = (size_t)(bm + rA0) * K + gsrc * 8;
    const size_t aoff1 = (size_t)(bm + rA1) * K + gsrc * 8;
    int gb0 = bn + rA0, gb1 = bn + rA1;
    if (GN) { gb0 = (gb0 < Nv) ? gb0 : (Nv - 1); gb1 = (gb1 < Nv) ? gb1 : (Nv - 1); }
    const size_t boff0 = (size_t)gb0 * K + gsrc * 8;
    const size_t boff1 = (size_t)gb1 * K + gsrc * 8;
    unsigned short* lA0 = &As[0][(w * 2 + 0) * 512];
    unsigned short* lA1 = &As[0][(w * 2 + 1) * 512];
    unsigned short* lB0 = &Bs[0][(w * 2 + 0) * 512];
    unsigned short* lB1 = &Bs[0][(w * 2 + 1) * 512];

    const int nt = K >> 5;

    f32x4 acc[8][4];
#pragma unroll
    for (int i = 0; i < 8; ++i)
#pragma unroll
        for (int j = 0; j < 4; ++j)
#pragma unroll
            for (int r = 0; r < 4; ++r) acc[i][j][r] = 0.f;

#pragma unroll
    for (int tp = 0; tp < 3; ++tp) {
        const int kp = tp << 5;
        gload16(A + aoff0 + kp, lA0 + tp * 8192);
        gload16(B + boff0 + kp, lB0 + tp * 8192);
        gload16(A + aoff1 + kp, lA1 + tp * 8192);
        gload16(B + boff1 + kp, lB1 + tp * 8192);
    }
    asm volatile("s_waitcnt vmcnt(8)" ::: "memory");
    asm volatile("s_barrier" ::: "memory");

    for (int t = 0; t < nt; ++t) {
        const int bt = t & 3;
        const unsigned short* as = As[bt];
        const unsigned short* bs = Bs[bt];
        const int pf = t + 3;
        const int kp = pf << 5;
        const int so = (pf & 3) * 8192;

        bfrag bfr[4], af[8];
#pragma unroll
        for (int ni = 0; ni < 4; ++ni) {
            int row = wc * 64 + ni * 16 + lr;
            bfr[ni] = *reinterpret_cast<const bfrag*>(&bs[row * 32 + ((g ^ slotk) * 8)]);
        }
#pragma unroll
        for (int mi = 0; mi < 8; ++mi) {
            int row = wr * 128 + mi * 16 + lr;
            af[mi] = *reinterpret_cast<const bfrag*>(&as[row * 32 + ((g ^ slotk) * 8)]);
        }
        if (pf < nt) {
            gload16(A + aoff0 + kp, lA0 + so);
            gload16(B + boff0 + kp, lB0 + so);
            gload16(A + aoff1 + kp, lA1 + so);
            gload16(B + boff1 + kp, lB1 + so);
        }
        __builtin_amdgcn_s_setprio(1);
#pragma unroll
        for (int mi = 0; mi < 8; ++mi)
#pragma unroll
            for (int ni = 0; ni < 4; ++ni)
                acc[mi][ni] = __builtin_amdgcn_mfma_f32_16x16x32_bf16(
                    af[mi], bfr[ni], acc[mi][ni], 0, 0, 0);
        __builtin_amdgcn_s_setprio(0);
        if (t + 3 < nt)      asm volatile("s_waitcnt vmcnt(8)" ::: "memory");
        else if (t + 2 < nt) asm volatile("s_waitcnt vmcnt(4)" ::: "memory");
        else if (t + 1 < nt) asm volatile("s_waitcnt vmcnt(0)" ::: "memory");
        asm volatile("s_barrier" ::: "memory");
    }

    unsigned short* Cb = (unsigned short*)Cp;
    float* Cf = (float*)Cp;
#pragma unroll
    for (int ni = 0; ni < 4; ++ni) {
        int col = bn + wc * 64 + ni * 16 + lr;
        if (GN && col >= Nv) continue;
        int gcol = ncol + col;
        float bi = bias[gcol];
#pragma unroll
        for (int mi = 0; mi < 8; ++mi) {
            int row0 = bm + wr * 128 + mi * 16 + g * 4;
#pragma unroll
            for (int r = 0; r < 4; ++r) {
                int row = row0 + r;
                float v = acc[mi][ni][r] + bi;
                if (EPI == 0) {
                    Cb[(size_t)row * ldc + gcol] = f2bf(v);
                } else if (EPI == 1) {
                    v = 0.5f * v * (1.0f + erff(v * 0.70710678118654752f));
                    Cb[(size_t)row * ldc + gcol] = f2bf(v);
                } else {
                    Cf[(size_t)row * ldc + gcol] = v;
                }
            }
        }
    }
}

// ================================================================ 128x128 pipelined GEMM
// 256 thr = 4 waves (2x2), per-wave 64x64. 64 KB LDS -> 2 blocks/CU.
// Same merged phase + counted vmcnt ring. EPI 0: bf16+bias. 2: f32 = R+acc+bias.
template<int EPI>
__global__ __launch_bounds__(256, 2)
void gemm128p(const unsigned short* __restrict__ A, const unsigned short* __restrict__ B,
              const float* __restrict__ bias, const float* __restrict__ R,
              void* __restrict__ Cp, int K, int ldc) {
    __shared__ unsigned short As[4][128 * 32];
    __shared__ unsigned short Bs[4][128 * 32];
    const int tid = threadIdx.x;
    const int lane = tid & 63, w = tid >> 6;
    const int wr = w >> 1, wc = w & 1;
    const int g = lane >> 4, lr = lane & 15;
    const int slotk = (lr >> 1) & 3;

    const int gx = gridDim.x;
    int flat = blockIdx.y * gx + blockIdx.x;
    int nwg = gx * gridDim.y;
    {
        int q = nwg >> 3, rr = nwg & 7;
        int xcd = flat & 7, pos = flat >> 3;
        flat = ((xcd < rr) ? (xcd * (q + 1)) : (rr * (q + 1) + (xcd - rr) * q)) + pos;
    }
    const int bm = (flat % gx) * 128;
    const int bn = (flat / gx) * 128;

    const int srow = lane >> 2;
    const int gsrc = (lane & 3) ^ ((lane >> 3) & 3);
    const int rA0 = (w * 2 + 0) * 16 + srow;
    const int rA1 = (w * 2 + 1) * 16 + srow;
    const size_t aoff0 = (size_t)(bm + rA0) * K + gsrc * 8;
    const size_t aoff1 = (size_t)(bm + rA1) * K + gsrc * 8;
    const size_t boff0 = (size_t)(bn + rA0) * K + gsrc * 8;
    const size_t boff1 = (size_t)(bn + rA1) * K + gsrc * 8;
    unsigned short* lA0 = &As[0][(w * 2 + 0) * 512];
    unsigned short* lA1 = &As[0][(w * 2 + 1) * 512];
    unsigned short* lB0 = &Bs[0][(w * 2 + 0) * 512];
    unsigned short* lB1 = &Bs[0][(w * 2 + 1) * 512];

    const int nt = K >> 5;

    f32x4 acc[4][4];
#pragma unroll
    for (int i = 0; i < 4; ++i)
#pragma unroll
        for (int j = 0; j < 4; ++j)
#pragma unroll
            for (int r = 0; r < 4; ++r) acc[i][j][r] = 0.f;

#pragma unroll
    for (int tp = 0; tp < 3; ++tp) {
        const int kp = tp << 5;
        gload16(A + aoff0 + kp, lA0 + tp * 4096);
        gload16(B + boff0 + kp, lB0 + tp * 4096);
        gload16(A + aoff1 + kp, lA1 + tp * 4096);
        gload16(B + boff1 + kp, lB1 + tp * 4096);
    }
    asm volatile("s_waitcnt vmcnt(8)" ::: "memory");
    asm volatile("s_barrier" ::: "memory");

    for (int t = 0; t < nt; ++t) {
        const int bt = t & 3;
        const unsigned short* as = As[bt];
        const unsigned short* bs = Bs[bt];
        const int pf = t + 3;
        const int kp = pf << 5;
        const int so = (pf & 3) * 4096;

        bfrag af[4], bfr[4];
#pragma unroll
        for (int i = 0; i < 4; ++i) {
            int ra = wr * 64 + i * 16 + lr;
            af[i] = *reinterpret_cast<const bfrag*>(&as[ra * 32 + ((g ^ slotk) * 8)]);
            int rb = wc * 64 + i * 16 + lr;
            bfr[i] = *reinterpret_cast<const bfrag*>(&bs[rb * 32 + ((g ^ slotk) * 8)]);
        }
        if (pf < nt) {
            gload16(A + aoff0 + kp, lA0 + so);
            gload16(B + boff0 + kp, lB0 + so);
            gload16(A + aoff1 + kp, lA1 + so);
            gload16(B + boff1 + kp, lB1 + so);
        }
        __builtin_amdgcn_s_setprio(1);
#pragma unroll
        for (int mi = 0; mi < 4; ++mi)
#pragma unroll
            for (int ni = 0; ni < 4; ++ni)
                acc[mi][ni] = __builtin_amdgcn_mfma_f32_16x16x32_bf16(
                    af[mi], bfr[ni], acc[mi][ni], 0, 0, 0);
        __builtin_amdgcn_s_setprio(0);
        if (t + 3 < nt)      asm volatile("s_waitcnt vmcnt(8)" ::: "memory");
        else if (t + 2 < nt) asm volatile("s_waitcnt vmcnt(4)" ::: "memory");
        else if (t + 1 < nt) asm volatile("s_waitcnt vmcnt(0)" ::: "memory");
        asm volatile("s_barrier" ::: "memory");
    }

    unsigned short* Cb = (unsigned short*)Cp;
    float* Cf = (float*)Cp;
#pragma unroll
    for (int ni = 0; ni < 4; ++ni) {
        int col = bn + wc * 64 + ni * 16 + lr;
        float bi = bias[col];
#pragma unroll
        for (int mi = 0; mi < 4; ++mi) {
            int row0 = bm + wr * 64 + mi * 16 + g * 4;
#pragma unroll
            for (int r = 0; r < 4; ++r) {
                int row = row0 + r;
                float v = acc[mi][ni][r] + bi;
                if (EPI == 0) {
                    Cb[(size_t)row * ldc + col] = f2bf(v);
                } else {
                    Cf[(size_t)row * ldc + col] = R[(size_t)row * ldc + col] + v;
                }
            }
        }
    }
}

// ---------------------------------------------------------------- MFMA attention
__global__ __launch_bounds__(256)
void attn_mfma(const unsigned short* __restrict__ qkv, unsigned short* __restrict__ ob) {
    const int bq = blockIdx.x;
    const int h = blockIdx.y;
    const int b = blockIdx.z;
    const int tid = threadIdx.x, lane = tid & 63, w = tid >> 6;
    const int g = lane >> 4, lr = lane & 15;
    const int qg0 = bq * 128 + w * 32;

    __shared__ unsigned short Kt[64 * 72];
    __shared__ unsigned short Vt[64 * 72];
    __shared__ unsigned short Pl[4][32 * 72];
    unsigned short* Plw = Pl[w];

    bfrag aq[2][2];
#pragma unroll
    for (int qs = 0; qs < 2; ++qs)
#pragma unroll
        for (int ks = 0; ks < 2; ++ks) {
            int row = qg0 + qs * 16 + lr;
            aq[qs][ks] = *reinterpret_cast<const bfrag*>(
                &qkv[(size_t)(b * Tt + row) * 3072 + h * 64 + ks * 32 + g * 8]);
        }

    float mrow[2][4], lrow[2][4], osc[2][4];
    f32x4 oacc[2][4];
#pragma unroll
    for (int qs = 0; qs < 2; ++qs)
#pragma unroll
        for (int r = 0; r < 4; ++r) { mrow[qs][r] = -3.0e38f; lrow[qs][r] = 0.f; }
#pragma unroll
    for (int qs = 0; qs < 2; ++qs)
#pragma unroll
        for (int dn = 0; dn < 4; ++dn)
#pragma unroll
            for (int r = 0; r < 4; ++r) oacc[qs][dn][r] = 0.f;

    const int ntile = 2 * bq + 2;
    for (int kt = 0; kt < ntile; ++kt) {
        {
            int row = tid >> 2, seg = tid & 3;
            const unsigned short* sk =
                &qkv[(size_t)(b * Tt + kt * 64 + row) * 3072 + Dm + h * 64 + seg * 16];
            bfrag kv0 = *(const bfrag*)sk;
            bfrag kv1 = *(const bfrag*)(sk + 8);
            *reinterpret_cast<bfrag*>(&Kt[row * 72 + seg * 16]) = kv0;
            *reinterpret_cast<bfrag*>(&Kt[row * 72 + seg * 16 + 8]) = kv1;
            const uint4* sv = reinterpret_cast<const uint4*>(
                &qkv[(size_t)(b * Tt + kt * 64 + row) * 3072 + 2 * Dm + h * 64 + seg * 16]);
            uint4 u0 = sv[0], u1 = sv[1];
            uint4 a, r0, r1;
            a.x = (seg & 1) ? u0.y : u0.x; a.y = (seg & 1) ? u0.z : u0.y;
            a.z = (seg & 1) ? u0.w : u0.z; a.w = (seg & 1) ? u0.x : u0.w;
            r0.x = (seg & 2) ? a.z : a.x; r0.y = (seg & 2) ? a.w : a.y;
            r0.z = (seg & 2) ? a.x : a.z; r0.w = (seg & 2) ? a.y : a.w;
            a.x = (seg & 1) ? u1.y : u1.x; a.y = (seg & 1) ? u1.z : u1.y;
            a.z = (seg & 1) ? u1.w : u1.z; a.w = (seg & 1) ? u1.x : u1.w;
            r1.x = (seg & 2) ? a.z : a.x; r1.y = (seg & 2) ? a.w : a.y;
            r1.z = (seg & 2) ? a.x : a.z; r1.w = (seg & 2) ? a.y : a.w;
            unsigned w0[4] = {r0.x, r0.y, r0.z, r0.w};
            unsigned w1[4] = {r1.x, r1.y, r1.z, r1.w};
#pragma unroll
            for (int i = 0; i < 8; ++i) {
                int j = (i + 2 * seg) & 7;
                unsigned ww = w0[i >> 1];
                unsigned short val = (i & 1) ? (unsigned short)(ww >> 16)
                                             : (unsigned short)(ww & 0xffff);
                Vt[(seg * 16 + j) * 72 + row] = val;
            }
#pragma unroll
            for (int i = 0; i < 8; ++i) {
                int j = (i + 2 * seg) & 7;
                unsigned ww = w1[i >> 1];
                unsigned short val = (i & 1) ? (unsigned short)(ww >> 16)
                                             : (unsigned short)(ww & 0xffff);
                Vt[(seg * 16 + 8 + j) * 72 + row] = val;
            }
        }
        __syncthreads();

        bool active = (kt * 64 <= qg0 + 31);
        if (active) {
            f32x4 s[2][4];
#pragma unroll
            for (int qs = 0; qs < 2; ++qs)
#pragma unroll
                for (int n = 0; n < 4; ++n)
#pragma unroll
                    for (int r = 0; r < 4; ++r) s[qs][n][r] = 0.f;
            bfrag bk[4][2];
#pragma unroll
            for (int n = 0; n < 4; ++n)
#pragma unroll
                for (int ks = 0; ks < 2; ++ks)
                    bk[n][ks] = *reinterpret_cast<const bfrag*>(
                        &Kt[(n * 16 + lr) * 72 + ks * 32 + g * 8]);
#pragma unroll
            for (int qs = 0; qs < 2; ++qs)
#pragma unroll
                for (int n = 0; n < 4; ++n)
#pragma unroll
                    for (int ks = 0; ks < 2; ++ks)
                        s[qs][n] = __builtin_amdgcn_mfma_f32_16x16x32_bf16(
                            aq[qs][ks], bk[n][ks], s[qs][n], 0, 0, 0);

            bool mayMask = (kt * 64 + 63 > qg0);
            float pv[2][4][4];
#pragma unroll
            for (int qs = 0; qs < 2; ++qs) {
#pragma unroll
                for (int r = 0; r < 4; ++r) {
                    int qrow = qg0 + qs * 16 + g * 4 + r;
                    float v[4];
#pragma unroll
                    for (int n = 0; n < 4; ++n) {
                        float sv = s[qs][n][r] * 0.125f;
                        if (mayMask && (kt * 64 + n * 16 + lr > qrow)) sv = -3.0e38f;
                        v[n] = sv;
                    }
                    float tmax = fmaxf(fmaxf(v[0], v[1]), fmaxf(v[2], v[3]));
                    tmax = fmaxf(tmax, __shfl_xor(tmax, 1));
                    tmax = fmaxf(tmax, __shfl_xor(tmax, 2));
                    tmax = fmaxf(tmax, __shfl_xor(tmax, 4));
                    tmax = fmaxf(tmax, __shfl_xor(tmax, 8));
                    float mold = mrow[qs][r];
                    float mnew = fmaxf(mold, tmax);
                    float scl = expf(mold - mnew);
                    float psum = 0.f;
#pragma unroll
                    for (int n = 0; n < 4; ++n) {
                        float p = expf(v[n] - mnew);
                        pv[qs][n][r] = p;
                        psum += p;
                    }
                    psum += __shfl_xor(psum, 1);
                    psum += __shfl_xor(psum, 2);
                    psum += __shfl_xor(psum, 4);
                    psum += __shfl_xor(psum, 8);
                    lrow[qs][r] = lrow[qs][r] * scl + psum;
                    mrow[qs][r] = mnew;
                    osc[qs][r] = scl;
                }
            }
#pragma unroll
            for (int qs = 0; qs < 2; ++qs)
#pragma unroll
                for (int dn = 0; dn < 4; ++dn)
#pragma unroll
                    for (int r = 0; r < 4; ++r) oacc[qs][dn][r] *= osc[qs][r];
#pragma unroll
            for (int qs = 0; qs < 2; ++qs)
#pragma unroll
                for (int n = 0; n < 4; ++n)
#pragma unroll
                    for (int r = 0; r < 4; ++r)
                        Plw[(qs * 16 + g * 4 + r) * 72 + n * 16 + lr] = f2bf(pv[qs][n][r]);
            asm volatile("s_waitcnt lgkmcnt(0)" ::: "memory");
            bfrag ap[2][2], bv[4][2];
#pragma unroll
            for (int qs = 0; qs < 2; ++qs)
#pragma unroll
                for (int ks = 0; ks < 2; ++ks)
                    ap[qs][ks] = *reinterpret_cast<const bfrag*>(
                        &Plw[(qs * 16 + lr) * 72 + ks * 32 + g * 8]);
#pragma unroll
            for (int dn = 0; dn < 4; ++dn)
#pragma unroll
                for (int ks = 0; ks < 2; ++ks)
                    bv[dn][ks] = *reinterpret_cast<const bfrag*>(
                        &Vt[(dn * 16 + lr) * 72 + ks * 32 + g * 8]);
#pragma unroll
            for (int qs = 0; qs < 2; ++qs)
#pragma unroll
                for (int dn = 0; dn < 4; ++dn)
#pragma unroll
                    for (int ks = 0; ks < 2; ++ks)
                        oacc[qs][dn] = __builtin_amdgcn_mfma_f32_16x16x32_bf16(
                            ap[qs][ks], bv[dn][ks], oacc[qs][dn], 0, 0, 0);
        }
        __syncthreads();
    }

#pragma unroll
    for (int qs = 0; qs < 2; ++qs)
#pragma unroll
        for (int r = 0; r < 4; ++r) {
            float rinv = 1.0f / lrow[qs][r];
            int qrow = qg0 + qs * 16 + g * 4 + r;
#pragma unroll
            for (int dn = 0; dn < 4; ++dn)
                ob[(size_t)(b * Tt + qrow) * Dm + h * 64 + dn * 16 + lr] =
                    f2bf(oacc[qs][dn][r] * rinv);
        }
}

// ---------------------------------------------------------------- loss (single-pass online LSE)
__global__ __launch_bounds__(512)
void loss_row_kernel(float* __restrict__ nll, const float* __restrict__ logits,
                     const int* __restrict__ targets) {
    const int row = blockIdx.x;
    const int tid = threadIdx.x;
    const int lane = tid & 63, wv = tid >> 6;
    const float* lr = logits + (size_t)row * Vv;

    const int lead = (4 - (row & 3)) & 3;
    const int nvec = (Vv - lead) >> 2;
    const int tail = Vv - lead - (nvec << 2);

    float m = -3.0e38f, s = 0.f;
    if (tid < lead) {
        float v = lr[tid];
        m = v; s = 1.f;
    }
    for (int k = tid; k < nvec; k += 512) {
        float4 v = *reinterpret_cast<const float4*>(lr + lead + (k << 2));
        float tm = fmaxf(fmaxf(v.x, v.y), fmaxf(v.z, v.w));
        float nm = fmaxf(m, tm);
        s = s * __expf(m - nm)
          + __expf(v.x - nm) + __expf(v.y - nm) + __expf(v.z - nm) + __expf(v.w - nm);
        m = nm;
    }
    if (tid < tail) {
        float v = lr[lead + (nvec << 2) + tid];
        float nm = fmaxf(m, v);
        s = s * __expf(m - nm) + __expf(v - nm);
        m = nm;
    }
#pragma unroll
    for (int off = 1; off < 64; off <<= 1) {
        float om = __shfl_xor(m, off);
        float os = __shfl_xor(s, off);
        float nm = fmaxf(m, om);
        s = s * __expf(m - nm) + os * __expf(om - nm);
        m = nm;
    }
    __shared__ float rm[8], rs[8];
    if (lane == 0) { rm[wv] = m; rs[wv] = s; }
    __syncthreads();
    if (tid == 0) {
        float M = rm[0];
#pragma unroll
        for (int i = 1; i < 8; ++i) M = fmaxf(M, rm[i]);
        float S = 0.f;
#pragma unroll
        for (int i = 0; i < 8; ++i) S += rs[i] * __expf(rm[i] - M);
        float lse = M + __logf(S);
        nll[row] = lse - lr[targets[row]];
    }
}

__global__ __launch_bounds__(256)
void loss_reduce_kernel(float* __restrict__ loss, const float* __restrict__ nll) {
    int tid = threadIdx.x;
    __shared__ float red[256];
    float s = 0.f;
    for (int j = tid; j < Mrows; j += 256) s += nll[j];
    red[tid] = s;
    __syncthreads();
    for (int st = 128; st > 0; st >>= 1) {
        if (tid < st) red[tid] += red[tid + st];
        __syncthreads();
    }
    if (tid == 0) *loss = red[0] * (1.0f / Mrows);
}

// ---------------------------------------------------------------- launch
extern "C" void kernel_launch(void* const* d_in, const int* in_sizes, int n_in,
                              void* d_out, int out_size, void* d_ws, size_t ws_size,
                              hipStream_t stream) {
    const int* idx = (const int*)d_in[0];
    const int* targets = (const int*)d_in[1];
    const float* wte = (const float*)d_in[2];
    const float* wpe = (const float*)d_in[3];
    const float* ln1_w = (const float*)d_in[4];
    const float* ln1_b = (const float*)d_in[5];
    const float* qkv_w = (const float*)d_in[6];
    const float* qkv_b = (const float*)d_in[7];
    const float* o_w = (const float*)d_in[8];
    const float* o_b = (const float*)d_in[9];
    const float* ln2_w = (const float*)d_in[10];
    const float* ln2_b = (const float*)d_in[11];
    const float* up_w = (const float*)d_in[12];
    const float* up_b = (const float*)d_in[13];
    const float* down_w = (const float*)d_in[14];
    const float* down_b = (const float*)d_in[15];
    const float* lnf_w = (const float*)d_in[16];
    const float* lnf_b = (const float*)d_in[17];
    const float* lm_b = (const float*)d_in[18];

    float* logits = (float*)d_out;
    char* ws = (char*)d_ws;
    const size_t MB = 1 << 20;
    float* x            = (float*)(ws);                       // 16 MB
    unsigned short* y   = (unsigned short*)(ws + 16 * MB);    // 8 MB
    unsigned short* qkv = (unsigned short*)(ws + 24 * MB);    // 24 MB
    unsigned short* ob  = (unsigned short*)(ws + 48 * MB);    // 8 MB
    unsigned short* up  = (unsigned short*)(ws + 56 * MB);    // 32 MB
    unsigned short* wTq = (unsigned short*)(ws + 88 * MB);    // 6.3 MB
    unsigned short* wTo = (unsigned short*)(ws + 96 * MB);    // 2.1 MB
    unsigned short* wTu = (unsigned short*)(ws + 100 * MB);   // 8.4 MB
    unsigned short* wTd = (unsigned short*)(ws + 112 * MB);   // 8.4 MB
    float* nll          = (float*)(ws + 127 * MB);            // 16 KB
    unsigned short* wbf = (unsigned short*)(ws + 24 * MB);    // lm phase (reuses qkv..)

    embed_kernel<<<Mrows, 256, 0, stream>>>(x, wte, wpe, idx);

    for (int l = 0; l < Ll; ++l) {
        ln_kernel<<<Mrows, 256, 0, stream>>>(y, x, ln1_w + l * Dm, ln1_b + l * Dm);
        transpose_layer<<<12288, 256, 0, stream>>>(
            qkv_w + (size_t)l * Dm * 3 * Dm, o_w + (size_t)l * Dm * Dm,
            up_w + (size_t)l * Dm * 4 * Dm, down_w + (size_t)l * 4 * Dm * Dm,
            wTq, wTo, wTu, wTd);
        gemm128p<0><<<dim3(Mrows / 128, 3 * Dm / 128), 256, 0, stream>>>(
            y, wTq, qkv_b + (size_t)l * 3 * Dm, nullptr, qkv, Dm, 3 * Dm);
        attn_mfma<<<dim3(8, Hh, Bb), 256, 0, stream>>>(qkv, ob);
        gemm128p<2><<<dim3(Mrows / 128, Dm / 128), 256, 0, stream>>>(
            ob, wTo, o_b + (size_t)l * Dm, x, x, Dm, Dm);
        ln_kernel<<<Mrows, 256, 0, stream>>>(y, x, ln2_w + l * Dm, ln2_b + l * Dm);
        gemm256<1, 0><<<dim3(Mrows / 256, 4 * Dm / 256), 512, 0, stream>>>(
            y, wTu, up_b + (size_t)l * 4 * Dm, up, 4 * Dm, Dm, 4 * Dm, 0);
        gemm128p<2><<<dim3(Mrows / 128, Dm / 128), 256, 0, stream>>>(
            up, wTd, down_b + (size_t)l * Dm, x, x, 4 * Dm, Dm);
    }

    ln_kernel<<<Mrows, 256, 0, stream>>>(y, x, lnf_w, lnf_b);

    cvt_rows<<<Vv, 128, 0, stream>>>(wbf, wte);
    gemm256<3, 1><<<dim3(Mrows / 256, (Vv + 255) / 256), 512, 0, stream>>>(
        y, wbf, lm_b, logits, Vv, Dm, Vv, 0);

    loss_row_kernel<<<Mrows, 512, 0, stream>>>(nll, logits, targets);
    loss_reduce_kernel<<<1, 256, 0, stream>>>(logits + (size_t)Mrows * Vv, nll);
}